// Round 5
// baseline (1641.182 us; speedup 1.0000x reference)
//
#include <hip/hip_runtime.h>
#include <hip/hip_bf16.h>

// N=200000, E=3200000, R=8, B=2, IN=128, H=32, OUT=128, U=10000, T=50000.

typedef float f4 __attribute__((ext_vector_type(4)));

// ---------------------------------------------------------------------------
// Layer-0 basis projection + self-loop GEMM: [N x 128] @ [128 x 96].
// cols 0..63 -> hb[n][64]; cols 64..95 -> h0[n][32] = x@loop + bias (agg init).
// 384 threads = 16 node-groups x 24 col-groups; 64 nodes/block; 49KB LDS ->
// 3 blocks/CU (18 waves/CU) vs round-3's 192-thread 2-block config.
template<int DIN>
__global__ __launch_bounds__(384, 4)
void k_hb(const float* __restrict__ h, const float* __restrict__ V,
          const float* __restrict__ loopw, const float* __restrict__ bias,
          float* __restrict__ hb, float* __restrict__ agg, int nNodes)
{
    __shared__ float CW[DIN * 96];
    for (int idx = threadIdx.x; idx < DIN * 96; idx += 384) {
        int i = idx / 96, c = idx % 96;
        CW[idx] = (c < 64) ? V[(c >> 5) * DIN * 32 + i * 32 + (c & 31)]
                           : loopw[i * 32 + (c - 64)];
    }
    __syncthreads();

    const int cg = threadIdx.x % 24;
    const int ng = threadIdx.x / 24;
    const int c0 = cg * 4;
    const int base = blockIdx.x * 64 + ng * 4;
    if (base >= nNodes) return;

    const float* hp[4];
    #pragma unroll
    for (int j = 0; j < 4; ++j)
        hp[j] = h + (long)min(base + j, nNodes - 1) * DIN;

    float acc[4][4] = {};
    for (int i = 0; i < DIN; i += 4) {
        f4 w0 = *(const f4*)&CW[(i + 0) * 96 + c0];
        f4 w1 = *(const f4*)&CW[(i + 1) * 96 + c0];
        f4 w2 = *(const f4*)&CW[(i + 2) * 96 + c0];
        f4 w3 = *(const f4*)&CW[(i + 3) * 96 + c0];
        #pragma unroll
        for (int j = 0; j < 4; ++j) {
            f4 hv = *(const f4*)(hp[j] + i);
            #pragma unroll
            for (int q = 0; q < 4; ++q)
                acc[j][q] = fmaf(hv[3], w3[q],
                            fmaf(hv[2], w2[q],
                            fmaf(hv[1], w1[q],
                            fmaf(hv[0], w0[q], acc[j][q]))));
        }
    }

    if (c0 < 64) {
        #pragma unroll
        for (int j = 0; j < 4; ++j)
            if (base + j < nNodes) {
                f4 v = {acc[j][0], acc[j][1], acc[j][2], acc[j][3]};
                *(f4*)(hb + (long)(base + j) * 64 + c0) = v;
            }
    } else {
        f4 bv = *(const f4*)(bias + (c0 - 64));
        #pragma unroll
        for (int j = 0; j < 4; ++j)
            if (base + j < nNodes) {
                f4 v = {acc[j][0] + bv[0], acc[j][1] + bv[1],
                        acc[j][2] + bv[2], acc[j][3] + bv[3]};
                *(f4*)(agg + (long)(base + j) * 32 + (c0 - 64)) = v;
            }
    }
}

// ---------------------------------------------------------------------------
// Bucketed CSR build. Buckets of 256 dst nodes; NB = ceil(N/256) = 782.
// Stage 1: bucket histogram (LDS-aggregated).
// Stage 2: single-block scan -> bbase (in-place on bcnt) + bcur init.
// Stage 3: append-scatter edges into bucket regions (cursor appends cluster
//          on the same cache lines -> write ~= payload, not 64B/edge).
// Stage 4: one block per bucket: LDS histogram + scan -> rowptr, then
//          LDS-cursor scatter into final packed (16KB window, cache-resident).
__global__ __launch_bounds__(256)
void k_zeroi(int* __restrict__ p, int n)
{
    int i = blockIdx.x * 256 + threadIdx.x;
    if (i < n) p[i] = 0;
}

__global__ __launch_bounds__(256)
void k_bhist(const int* __restrict__ dst, int* __restrict__ bcnt, int nEdges, int nB)
{
    __shared__ int hloc[1024];
    for (int i = threadIdx.x; i < nB; i += 256) hloc[i] = 0;
    __syncthreads();
    for (int e = blockIdx.x * 256 + threadIdx.x; e < nEdges; e += gridDim.x * 256)
        atomicAdd(&hloc[dst[e] >> 8], 1);
    __syncthreads();
    for (int i = threadIdx.x; i < nB; i += 256)
        if (hloc[i]) atomicAdd(&bcnt[i], hloc[i]);
}

__global__ __launch_bounds__(1024)
void k_bscan(int* __restrict__ bcnt, int* __restrict__ bcur,
             int* __restrict__ rowptr, int nB, int nNodes, int nEdges)
{
    __shared__ int s[1024];
    int t = threadIdx.x;
    int v = (t < nB) ? bcnt[t] : 0;
    s[t] = v; __syncthreads();
    for (int off = 1; off < 1024; off <<= 1) {
        int tmp = (t >= off) ? s[t - off] : 0;
        __syncthreads();
        s[t] += tmp;
        __syncthreads();
    }
    if (t < nB) {
        int ex = s[t] - v;
        bcnt[t] = ex;          // becomes bbase
        bcur[t] = ex;
    }
    if (t == 0) {
        bcnt[nB] = nEdges;     // bbase[nB]
        rowptr[nNodes] = nEdges;
    }
}

__global__ __launch_bounds__(256)
void k_bscatter(const int* __restrict__ src, const int* __restrict__ dst,
                const int* __restrict__ et, int* __restrict__ bcur,
                unsigned* __restrict__ bpk, int nEdges)
{
    int e = blockIdx.x * 256 + threadIdx.x;
    if (e >= nEdges) return;
    int d = dst[e];
    int pos = atomicAdd(&bcur[d >> 8], 1);
    bpk[pos] = ((unsigned)(d & 255) << 21) | ((unsigned)src[e] << 3) | (unsigned)et[e];
}

__global__ __launch_bounds__(256)
void k_bucket(const unsigned* __restrict__ bpk, const int* __restrict__ bbase,
              int* __restrict__ rowptr, unsigned* __restrict__ packed, int nNodes)
{
    __shared__ int s[256];
    __shared__ int cur[256];
    const int b = blockIdx.x;
    const int t = threadIdx.x;
    const int ebeg = bbase[b], eend = bbase[b + 1];

    cur[t] = 0;
    __syncthreads();
    for (int j = ebeg + t; j < eend; j += 256)
        atomicAdd(&cur[bpk[j] >> 21], 1);
    __syncthreads();
    int v = cur[t];
    s[t] = v; __syncthreads();
    for (int off = 1; off < 256; off <<= 1) {
        int tmp = (t >= off) ? s[t - off] : 0;
        __syncthreads();
        s[t] += tmp;
        __syncthreads();
    }
    int ex = s[t] - v;
    int node = b * 256 + t;
    if (node < nNodes) rowptr[node] = ebeg + ex;
    cur[t] = ex;
    __syncthreads();
    for (int j = ebeg + t; j < eend; j += 256) {
        unsigned p = bpk[j];
        int pos = ebeg + atomicAdd(&cur[p >> 21], 1);
        packed[pos] = p & 0x1FFFFFu;
    }
}

// ---------------------------------------------------------------------------
// Layer-0 pull: one wave per node, lanes 0..31 & 32..63 split the edge list.
__global__ __launch_bounds__(256)
void k_pull0(const int* __restrict__ rowptr, const unsigned* __restrict__ packed,
             const float* __restrict__ comb, const float* __restrict__ hb,
             float* __restrict__ h0, int nNodes)
{
    __shared__ float sc[16];
    if (threadIdx.x < 16) sc[threadIdx.x] = comb[threadIdx.x];
    __syncthreads();
    int n = blockIdx.x * 4 + (threadIdx.x >> 6);
    if (n >= nNodes) return;
    int lane = threadIdx.x & 63, o = lane & 31, half = lane >> 5;
    int beg = rowptr[n], end = rowptr[n + 1];
    float acc = 0.f;
    int j = beg + half;
    for (; j + 2 < end; j += 4) {
        unsigned pa = packed[j], pb = packed[j + 2];
        const float* ha = hb + (long)(pa >> 3) * 64;
        const float* hc = hb + (long)(pb >> 3) * 64;
        float a0 = ha[o], a1 = ha[32 + o];
        float b0 = hc[o], b1 = hc[32 + o];
        int ra = (pa & 7) * 2, rb = (pb & 7) * 2;
        acc = fmaf(sc[ra], a0, fmaf(sc[ra + 1], a1, acc));
        acc = fmaf(sc[rb], b0, fmaf(sc[rb + 1], b1, acc));
    }
    if (j < end) {
        unsigned pa = packed[j];
        const float* ha = hb + (long)(pa >> 3) * 64;
        int ra = (pa & 7) * 2;
        acc = fmaf(sc[ra], ha[o], fmaf(sc[ra + 1], ha[32 + o], acc));
    }
    acc += __shfl_xor(acc, 32);
    if (half == 0) {
        float* p = h0 + (long)n * 32 + o;
        *p = tanhf(*p + acc);
    }
}

// ---------------------------------------------------------------------------
// Layers 1/2 pull in INPUT space: u[n][b][i] = sum_e comb[r,b] * hsrc[s][i].
__global__ __launch_bounds__(256)
void k_pull_u(const int* __restrict__ rowptr, const unsigned* __restrict__ packed,
              const float* __restrict__ comb, const float* __restrict__ hsrc,
              float* __restrict__ u, int nNodes)
{
    __shared__ float sc[16];
    if (threadIdx.x < 16) sc[threadIdx.x] = comb[threadIdx.x];
    __syncthreads();
    int n = blockIdx.x * 4 + (threadIdx.x >> 6);
    if (n >= nNodes) return;
    int lane = threadIdx.x & 63, i = lane & 31, half = lane >> 5;
    int beg = rowptr[n], end = rowptr[n + 1];
    float u0 = 0.f, u1 = 0.f;
    int j = beg + half;
    for (; j + 2 < end; j += 4) {
        unsigned pa = packed[j], pb = packed[j + 2];
        float ha = hsrc[(long)(pa >> 3) * 32 + i];
        float hc = hsrc[(long)(pb >> 3) * 32 + i];
        int ra = (pa & 7) * 2, rb = (pb & 7) * 2;
        u0 = fmaf(sc[ra], ha, u0);  u1 = fmaf(sc[ra + 1], ha, u1);
        u0 = fmaf(sc[rb], hc, u0);  u1 = fmaf(sc[rb + 1], hc, u1);
    }
    if (j < end) {
        unsigned pa = packed[j];
        float ha = hsrc[(long)(pa >> 3) * 32 + i];
        int ra = (pa & 7) * 2;
        u0 = fmaf(sc[ra], ha, u0);  u1 = fmaf(sc[ra + 1], ha, u1);
    }
    u0 += __shfl_xor(u0, 32);
    u1 += __shfl_xor(u1, 32);
    if (half == 0) {
        u[(long)n * 64 + i]      = u0;
        u[(long)n * 64 + 32 + i] = u1;
    }
}

// ---------------------------------------------------------------------------
// Post GEMM for layers 1/2: hdst = tanh([u0|u1|hsrc] @ [V0;V1;loop] + bias).
__global__ __launch_bounds__(256, 2)
void k_post(const float* __restrict__ u, const float* __restrict__ hsrc,
            const float* __restrict__ V, const float* __restrict__ loopw,
            const float* __restrict__ bias, float* __restrict__ hdst, int nNodes)
{
    __shared__ float CW[96 * 32];
    for (int idx = threadIdx.x; idx < 96 * 32; idx += 256) {
        int i = idx / 32, o = idx % 32;
        CW[idx] = (i < 64) ? V[i * 32 + o]
                           : loopw[(i - 64) * 32 + o];
    }
    __syncthreads();

    const int cg = threadIdx.x & 7;
    const int ng = threadIdx.x >> 3;
    const int c0 = cg * 4;
    const int base = blockIdx.x * 128 + ng * 4;
    if (base >= nNodes) return;

    long rows[4];
    #pragma unroll
    for (int j = 0; j < 4; ++j)
        rows[j] = (long)min(base + j, nNodes - 1);

    float acc[4][4] = {};
    #pragma unroll 2
    for (int i = 0; i < 96; i += 4) {
        f4 w0 = *(const f4*)&CW[(i + 0) * 32 + c0];
        f4 w1 = *(const f4*)&CW[(i + 1) * 32 + c0];
        f4 w2 = *(const f4*)&CW[(i + 2) * 32 + c0];
        f4 w3 = *(const f4*)&CW[(i + 3) * 32 + c0];
        #pragma unroll
        for (int j = 0; j < 4; ++j) {
            f4 hv = (i < 64) ? *(const f4*)(u + rows[j] * 64 + i)
                             : *(const f4*)(hsrc + rows[j] * 32 + (i - 64));
            #pragma unroll
            for (int q = 0; q < 4; ++q)
                acc[j][q] = fmaf(hv[3], w3[q],
                            fmaf(hv[2], w2[q],
                            fmaf(hv[1], w1[q],
                            fmaf(hv[0], w0[q], acc[j][q]))));
        }
    }

    f4 bv = *(const f4*)(bias + c0);
    #pragma unroll
    for (int j = 0; j < 4; ++j)
        if (base + j < nNodes) {
            f4 v = {tanhf(acc[j][0] + bv[0]), tanhf(acc[j][1] + bv[1]),
                    tanhf(acc[j][2] + bv[2]), tanhf(acc[j][3] + bv[3])};
            *(f4*)(hdst + (long)(base + j) * 32 + c0) = v;
        }
}

// ---------------------------------------------------------------------------
// Fused MLP heads + reparameterization, register-tiled (round-3 version).
__global__ __launch_bounds__(256, 2)
void k_mlp(const float* __restrict__ h0, const float* __restrict__ h1,
           const float* __restrict__ h2,
           const float* __restrict__ Wm1, const float* __restrict__ bm1,
           const float* __restrict__ Wm2, const float* __restrict__ bm2,
           const float* __restrict__ Ws1, const float* __restrict__ bs1,
           const float* __restrict__ Ws2, const float* __restrict__ bs2,
           const float* __restrict__ noise, float* __restrict__ z, int nNodes)
{
    __shared__ float sW1[2][96 * 32];
    __shared__ float sW2[2][32 * 128];
    __shared__ float sb1[2][32];
    __shared__ float sb2[2][128];
    __shared__ float shid[2][64][32];

    for (int i = threadIdx.x; i < 96 * 32; i += 256) { sW1[0][i] = Wm1[i]; sW1[1][i] = Ws1[i]; }
    for (int i = threadIdx.x; i < 32 * 128; i += 256) { sW2[0][i] = Wm2[i]; sW2[1][i] = Ws2[i]; }
    if (threadIdx.x < 32)  { sb1[0][threadIdx.x] = bm1[threadIdx.x]; sb1[1][threadIdx.x] = bs1[threadIdx.x]; }
    if (threadIdx.x < 128) { sb2[0][threadIdx.x] = bm2[threadIdx.x]; sb2[1][threadIdx.x] = bs2[threadIdx.x]; }
    __syncthreads();

    const int base = blockIdx.x * 64;
    if (base >= nNodes) return;

    // ---- phase A: hidden = relu(cs @ W1 + b1) ----
    {
        const int head = threadIdx.x >> 7;
        const int rem  = threadIdx.x & 127;
        const int ng   = rem >> 3;
        const int c0   = (rem & 7) * 4;
        const float* sW = sW1[head];
        long rows[4];
        #pragma unroll
        for (int j = 0; j < 4; ++j)
            rows[j] = (long)min(base + ng * 4 + j, nNodes - 1);

        float acc[4][4] = {};
        const float* hs[3] = {h0, h1, h2};
        #pragma unroll
        for (int part = 0; part < 3; ++part) {
            const float* hp = hs[part];
            #pragma unroll
            for (int kk = 0; kk < 32; kk += 4) {
                const int k = part * 32 + kk;
                f4 w0 = *(const f4*)&sW[(k + 0) * 32 + c0];
                f4 w1 = *(const f4*)&sW[(k + 1) * 32 + c0];
                f4 w2 = *(const f4*)&sW[(k + 2) * 32 + c0];
                f4 w3 = *(const f4*)&sW[(k + 3) * 32 + c0];
                #pragma unroll
                for (int j = 0; j < 4; ++j) {
                    f4 hv = *(const f4*)(hp + rows[j] * 32 + kk);
                    #pragma unroll
                    for (int q = 0; q < 4; ++q)
                        acc[j][q] = fmaf(hv[3], w3[q],
                                    fmaf(hv[2], w2[q],
                                    fmaf(hv[1], w1[q],
                                    fmaf(hv[0], w0[q], acc[j][q]))));
                }
            }
        }
        f4 bv = *(const f4*)&sb1[head][c0];
        #pragma unroll
        for (int j = 0; j < 4; ++j) {
            f4 v = {fmaxf(acc[j][0] + bv[0], 0.f), fmaxf(acc[j][1] + bv[1], 0.f),
                    fmaxf(acc[j][2] + bv[2], 0.f), fmaxf(acc[j][3] + bv[3], 0.f)};
            *(f4*)&shid[head][ng * 4 + j][c0] = v;
        }
    }
    __syncthreads();

    // ---- phase B: out = hid @ W2 + b2; z = mean + noise * exp(log_std) ----
    const int ng = threadIdx.x >> 5;
    const int c0 = (threadIdx.x & 31) * 4;
    #pragma unroll
    for (int pass = 0; pass < 2; ++pass) {
        const int nb = pass * 32 + ng * 4;
        float am[4][4] = {}, as_[4][4] = {};
        #pragma unroll 4
        for (int k = 0; k < 32; k += 4) {
            f4 wm0 = *(const f4*)&sW2[0][(k + 0) * 128 + c0];
            f4 wm1 = *(const f4*)&sW2[0][(k + 1) * 128 + c0];
            f4 wm2 = *(const f4*)&sW2[0][(k + 2) * 128 + c0];
            f4 wm3 = *(const f4*)&sW2[0][(k + 3) * 128 + c0];
            f4 ws0 = *(const f4*)&sW2[1][(k + 0) * 128 + c0];
            f4 ws1 = *(const f4*)&sW2[1][(k + 1) * 128 + c0];
            f4 ws2 = *(const f4*)&sW2[1][(k + 2) * 128 + c0];
            f4 ws3 = *(const f4*)&sW2[1][(k + 3) * 128 + c0];
            #pragma unroll
            for (int j = 0; j < 4; ++j) {
                f4 hm = *(const f4*)&shid[0][nb + j][k];
                f4 hv = *(const f4*)&shid[1][nb + j][k];
                #pragma unroll
                for (int q = 0; q < 4; ++q) {
                    am[j][q]  = fmaf(hm[3], wm3[q],
                                fmaf(hm[2], wm2[q],
                                fmaf(hm[1], wm1[q],
                                fmaf(hm[0], wm0[q], am[j][q]))));
                    as_[j][q] = fmaf(hv[3], ws3[q],
                                fmaf(hv[2], ws2[q],
                                fmaf(hv[1], ws1[q],
                                fmaf(hv[0], ws0[q], as_[j][q]))));
                }
            }
        }
        f4 b2m = *(const f4*)&sb2[0][c0];
        f4 b2s = *(const f4*)&sb2[1][c0];
        #pragma unroll
        for (int j = 0; j < 4; ++j) {
            const int n = base + nb + j;
            if (n < nNodes) {
                f4 nz = *(const f4*)(noise + (long)n * 128 + c0);
                f4 v;
                #pragma unroll
                for (int q = 0; q < 4; ++q)
                    v[q] = fmaf(nz[q], expf(as_[j][q] + b2s[q]), am[j][q] + b2m[q]);
                *(f4*)(z + (long)n * 128 + c0) = v;
            }
        }
    }
}

// ---------------------------------------------------------------------------
__global__ __launch_bounds__(256)
void k_pairs(const float* __restrict__ z, const int* __restrict__ ui,
             const int* __restrict__ ii, float* __restrict__ out, int U, int T)
{
    int w = (blockIdx.x * 256 + threadIdx.x) >> 6;
    int lane = threadIdx.x & 63;
    if (w >= U) return;
    int a = ui[w], b = ii[w];
    float a0 = z[(long)a * 128 + lane], a1 = z[(long)a * 128 + 64 + lane];
    float b0 = z[(long)b * 128 + lane], b1 = z[(long)b * 128 + 64 + lane];
    float* res = out + U + T;
    res[(long)w * 128 + lane] = a0;
    res[(long)w * 128 + 64 + lane] = a1;
    res[(long)(U + w) * 128 + lane] = b0;
    res[(long)(U + w) * 128 + 64 + lane] = b1;
    float d = fmaf(a0, b0, a1 * b1);
    #pragma unroll
    for (int off = 32; off; off >>= 1) d += __shfl_xor(d, off);
    if (lane == 0) out[w] = d;
}

__global__ __launch_bounds__(256)
void k_preds(const float* __restrict__ z, const int* __restrict__ ts,
             const int* __restrict__ td, float* __restrict__ out, int U, int T)
{
    int w = (blockIdx.x * 256 + threadIdx.x) >> 6;
    int lane = threadIdx.x & 63;
    if (w >= T) return;
    int a = ts[w], b = td[w];
    float a0 = z[(long)a * 128 + lane], a1 = z[(long)a * 128 + 64 + lane];
    float b0 = z[(long)b * 128 + lane], b1 = z[(long)b * 128 + 64 + lane];
    float d = fmaf(a0, b0, a1 * b1);
    #pragma unroll
    for (int off = 32; off; off >>= 1) d += __shfl_xor(d, off);
    if (lane == 0) out[U + w] = d;
}

// ---------------------------------------------------------------------------
extern "C" void kernel_launch(void* const* d_in, const int* in_sizes, int n_in,
                              void* d_out, int out_size, void* d_ws, size_t ws_size,
                              hipStream_t stream)
{
    const float* x     = (const float*)d_in[0];
    const int*   src   = (const int*)d_in[1];
    const int*   dst   = (const int*)d_in[2];
    const int*   et    = (const int*)d_in[3];
    const float* noise = (const float*)d_in[4];
    const int*   ui    = (const int*)d_in[5];
    const int*   ii    = (const int*)d_in[6];
    const int*   tes   = (const int*)d_in[7];
    const int*   ted   = (const int*)d_in[8];
    const float* V0    = (const float*)d_in[9];
    const float* comb0 = (const float*)d_in[10];
    const float* loop0 = (const float*)d_in[11];
    const float* b0    = (const float*)d_in[12];
    const float* V1    = (const float*)d_in[13];
    const float* comb1 = (const float*)d_in[14];
    const float* loop1 = (const float*)d_in[15];
    const float* b1    = (const float*)d_in[16];
    const float* V2    = (const float*)d_in[17];
    const float* comb2 = (const float*)d_in[18];
    const float* loop2 = (const float*)d_in[19];
    const float* b2    = (const float*)d_in[20];
    const float* Wm1   = (const float*)d_in[21];
    const float* bm1   = (const float*)d_in[22];
    const float* Wm2   = (const float*)d_in[23];
    const float* bm2   = (const float*)d_in[24];
    const float* Ws1   = (const float*)d_in[25];
    const float* bs1   = (const float*)d_in[26];
    const float* Ws2   = (const float*)d_in[27];
    const float* bs2   = (const float*)d_in[28];

    const int N = in_sizes[0] / 128;   // 200000
    const int E = in_sizes[1];         // 3200000
    const int U = in_sizes[5];
    const int T = in_sizes[7];
    const int NB = (N + 255) / 256;    // 782 buckets of 256 dst nodes

    float* out = (float*)d_out;

    // Workspace (floats): hb/u[N*64] | h0[N*32] | h1 | h2 | z[N*128]
    // CSR scratch aliases the z region (dead before k_mlp writes z):
    //   rowptr[N+1] | packed[E] | bpk[E] | bcnt/bbase[NB+1] | bcur[NB]
    float* ws = (float*)d_ws;
    float* hb = ws;
    float* h0 = hb + (long)N * 64;
    float* h1 = h0 + (long)N * 32;
    float* h2 = h1 + (long)N * 32;
    float* z  = h2 + (long)N * 32;
    int*      rowptr = (int*)z;
    unsigned* packed = (unsigned*)(rowptr + N + 1);
    unsigned* bpk    = packed + E;
    int*      bcnt   = (int*)(bpk + E);        // becomes bbase after scan
    int*      bcur   = bcnt + NB + 1;

    const int eBlocks    = (E + 255) / 256;
    const int hbBlocks   = (N + 63) / 64;
    const int pullBlocks = (N + 3) / 4;
    const int postBlocks = (N + 127) / 128;
    const int mlpBlocks  = (N + 63) / 64;

    // ---- bucketed CSR build (by dst), reused for all 3 layers ----
    k_zeroi<<<(NB + 256) / 256, 256, 0, stream>>>(bcnt, NB + 1);
    k_bhist<<<1024, 256, 0, stream>>>(dst, bcnt, E, NB);
    k_bscan<<<1, 1024, 0, stream>>>(bcnt, bcur, rowptr, NB, N, E);
    k_bscatter<<<eBlocks, 256, 0, stream>>>(src, dst, et, bcur, bpk, E);
    k_bucket<<<NB, 256, 0, stream>>>(bpk, bcnt, rowptr, packed, N);

    // ---- layer 0 ----
    k_hb<128><<<hbBlocks, 384, 0, stream>>>(x, V0, loop0, b0, hb, h0, N);
    k_pull0<<<pullBlocks, 256, 0, stream>>>(rowptr, packed, comb0, hb, h0, N);

    // ---- layer 1 ----
    k_pull_u<<<pullBlocks, 256, 0, stream>>>(rowptr, packed, comb1, h0, hb, N);
    k_post<<<postBlocks, 256, 0, stream>>>(hb, h0, V1, loop1, b1, h1, N);

    // ---- layer 2 ----
    k_pull_u<<<pullBlocks, 256, 0, stream>>>(rowptr, packed, comb2, h1, hb, N);
    k_post<<<postBlocks, 256, 0, stream>>>(hb, h1, V2, loop2, b2, h2, N);

    // ---- heads + reparameterization ----
    k_mlp<<<mlpBlocks, 256, 0, stream>>>(h0, h1, h2, Wm1, bm1, Wm2, bm2,
                                         Ws1, bs1, Ws2, bs2, noise, z, N);
    // ---- outputs ----
    k_pairs<<<(U * 64 + 255) / 256, 256, 0, stream>>>(z, ui, ii, out, U, T);
    k_preds<<<(T * 64 + 255) / 256, 256, 0, stream>>>(z, tes, ted, out, U, T);
}

// Round 6
// 948.336 us; speedup vs baseline: 1.7306x; 1.7306x over previous
//
#include <hip/hip_runtime.h>
#include <hip/hip_bf16.h>

// N=200000, E=3200000, R=8, B=2, IN=128, H=32, OUT=128, U=10000, T=50000.

typedef float f4 __attribute__((ext_vector_type(4)));

#define NBLK 256      // scatter blocks
#define MAXB 800      // >= NB = ceil(N/256) = 782

// ---------------------------------------------------------------------------
// Layer-0 basis projection + self-loop GEMM: [N x 128] @ [128 x 96].
template<int DIN>
__global__ __launch_bounds__(384, 4)
void k_hb(const float* __restrict__ h, const float* __restrict__ V,
          const float* __restrict__ loopw, const float* __restrict__ bias,
          float* __restrict__ hb, float* __restrict__ agg, int nNodes)
{
    __shared__ float CW[DIN * 96];
    for (int idx = threadIdx.x; idx < DIN * 96; idx += 384) {
        int i = idx / 96, c = idx % 96;
        CW[idx] = (c < 64) ? V[(c >> 5) * DIN * 32 + i * 32 + (c & 31)]
                           : loopw[i * 32 + (c - 64)];
    }
    __syncthreads();

    const int cg = threadIdx.x % 24;
    const int ng = threadIdx.x / 24;
    const int c0 = cg * 4;
    const int base = blockIdx.x * 64 + ng * 4;
    if (base >= nNodes) return;

    const float* hp[4];
    #pragma unroll
    for (int j = 0; j < 4; ++j)
        hp[j] = h + (long)min(base + j, nNodes - 1) * DIN;

    float acc[4][4] = {};
    for (int i = 0; i < DIN; i += 4) {
        f4 w0 = *(const f4*)&CW[(i + 0) * 96 + c0];
        f4 w1 = *(const f4*)&CW[(i + 1) * 96 + c0];
        f4 w2 = *(const f4*)&CW[(i + 2) * 96 + c0];
        f4 w3 = *(const f4*)&CW[(i + 3) * 96 + c0];
        #pragma unroll
        for (int j = 0; j < 4; ++j) {
            f4 hv = *(const f4*)(hp[j] + i);
            #pragma unroll
            for (int q = 0; q < 4; ++q)
                acc[j][q] = fmaf(hv[3], w3[q],
                            fmaf(hv[2], w2[q],
                            fmaf(hv[1], w1[q],
                            fmaf(hv[0], w0[q], acc[j][q]))));
        }
    }

    if (c0 < 64) {
        #pragma unroll
        for (int j = 0; j < 4; ++j)
            if (base + j < nNodes) {
                f4 v = {acc[j][0], acc[j][1], acc[j][2], acc[j][3]};
                *(f4*)(hb + (long)(base + j) * 64 + c0) = v;
            }
    } else {
        f4 bv = *(const f4*)(bias + (c0 - 64));
        #pragma unroll
        for (int j = 0; j < 4; ++j)
            if (base + j < nNodes) {
                f4 v = {acc[j][0] + bv[0], acc[j][1] + bv[1],
                        acc[j][2] + bv[2], acc[j][3] + bv[3]};
                *(f4*)(agg + (long)(base + j) * 32 + (c0 - 64)) = v;
            }
    }
}

// ---------------------------------------------------------------------------
// Contention-free bucketed CSR build (scan-based radix partition).
// Buckets of 256 dst nodes. hist[block][bucket] -> column scans -> bucket
// scan -> deterministic placement; no contended global atomics anywhere.

// Stage 1: per-block LDS histogram over buckets.
__global__ __launch_bounds__(256)
void k_bhist2(const int* __restrict__ dst, int* __restrict__ hist,
              int nEdges, int nB, int chunk)
{
    __shared__ int hloc[MAXB];
    for (int i = threadIdx.x; i < nB; i += 256) hloc[i] = 0;
    __syncthreads();
    const int ebeg = blockIdx.x * chunk;
    const int eend = min(ebeg + chunk, nEdges);
    for (int e = ebeg + threadIdx.x; e < eend; e += 256)
        atomicAdd(&hloc[dst[e] >> 8], 1);
    __syncthreads();
    for (int i = threadIdx.x; i < nB; i += 256)
        hist[blockIdx.x * MAXB + i] = hloc[i];
}

// Stage 2: one block per bucket: exclusive scan of its 256-entry column.
__global__ __launch_bounds__(256)
void k_colscan(const int* __restrict__ hist, int* __restrict__ base,
               int* __restrict__ colsum, int nB)
{
    __shared__ int s[256];
    const int b = blockIdx.x;
    const int t = threadIdx.x;
    int v = hist[t * MAXB + b];
    s[t] = v; __syncthreads();
    for (int off = 1; off < 256; off <<= 1) {
        int tmp = (t >= off) ? s[t - off] : 0;
        __syncthreads();
        s[t] += tmp;
        __syncthreads();
    }
    base[t * MAXB + b] = s[t] - v;       // exclusive within bucket
    if (t == 255) colsum[b] = s[255];
}

// Stage 3: exclusive scan of colsum -> bucketBase.
__global__ __launch_bounds__(1024)
void k_bscan2(const int* __restrict__ colsum, int* __restrict__ bb,
              int* __restrict__ rowptr, int nB, int nNodes, int nEdges)
{
    __shared__ int s[1024];
    int t = threadIdx.x;
    int v = (t < nB) ? colsum[t] : 0;
    s[t] = v; __syncthreads();
    for (int off = 1; off < 1024; off <<= 1) {
        int tmp = (t >= off) ? s[t - off] : 0;
        __syncthreads();
        s[t] += tmp;
        __syncthreads();
    }
    if (t < nB) bb[t] = s[t] - v;
    if (t == 0) { bb[nB] = nEdges; rowptr[nNodes] = nEdges; }
}

// Stage 4: scatter into bucket regions. Position = bb[b] + base[blk][b] +
// LDS cursor. Block's edges per bucket are contiguous -> coalesced lines.
__global__ __launch_bounds__(256)
void k_bscatter2(const int* __restrict__ src, const int* __restrict__ dst,
                 const int* __restrict__ et, const int* __restrict__ base,
                 const int* __restrict__ bb, unsigned* __restrict__ bpk,
                 int nEdges, int nB, int chunk)
{
    __shared__ int sbase[MAXB];
    __shared__ int cur[MAXB];
    for (int i = threadIdx.x; i < nB; i += 256) {
        sbase[i] = bb[i] + base[blockIdx.x * MAXB + i];
        cur[i] = 0;
    }
    __syncthreads();
    const int ebeg = blockIdx.x * chunk;
    const int eend = min(ebeg + chunk, nEdges);
    for (int e = ebeg + threadIdx.x; e < eend; e += 256) {
        int d = dst[e];
        int b = d >> 8;
        int r = atomicAdd(&cur[b], 1);
        bpk[sbase[b] + r] = ((unsigned)(d & 255) << 21)
                          | ((unsigned)src[e] << 3) | (unsigned)et[e];
    }
}

// Stage 5: one block per bucket: node-level rowptr + final packed order.
__global__ __launch_bounds__(256)
void k_bucket(const unsigned* __restrict__ bpk, const int* __restrict__ bbase,
              int* __restrict__ rowptr, unsigned* __restrict__ packed, int nNodes)
{
    __shared__ int s[256];
    __shared__ int cur[256];
    const int b = blockIdx.x;
    const int t = threadIdx.x;
    const int ebeg = bbase[b], eend = bbase[b + 1];

    cur[t] = 0;
    __syncthreads();
    for (int j = ebeg + t; j < eend; j += 256)
        atomicAdd(&cur[bpk[j] >> 21], 1);
    __syncthreads();
    int v = cur[t];
    s[t] = v; __syncthreads();
    for (int off = 1; off < 256; off <<= 1) {
        int tmp = (t >= off) ? s[t - off] : 0;
        __syncthreads();
        s[t] += tmp;
        __syncthreads();
    }
    int ex = s[t] - v;
    int node = b * 256 + t;
    if (node < nNodes) rowptr[node] = ebeg + ex;
    cur[t] = ex;
    __syncthreads();
    for (int j = ebeg + t; j < eend; j += 256) {
        unsigned p = bpk[j];
        int pos = ebeg + atomicAdd(&cur[p >> 21], 1);
        packed[pos] = p & 0x1FFFFFu;
    }
}

// ---------------------------------------------------------------------------
// Layer-0 pull: one wave per node, lanes 0..31 & 32..63 split the edge list.
__global__ __launch_bounds__(256)
void k_pull0(const int* __restrict__ rowptr, const unsigned* __restrict__ packed,
             const float* __restrict__ comb, const float* __restrict__ hb,
             float* __restrict__ h0, int nNodes)
{
    __shared__ float sc[16];
    if (threadIdx.x < 16) sc[threadIdx.x] = comb[threadIdx.x];
    __syncthreads();
    int n = blockIdx.x * 4 + (threadIdx.x >> 6);
    if (n >= nNodes) return;
    int lane = threadIdx.x & 63, o = lane & 31, half = lane >> 5;
    int beg = rowptr[n], end = rowptr[n + 1];
    float acc = 0.f;
    int j = beg + half;
    for (; j + 2 < end; j += 4) {
        unsigned pa = packed[j], pb = packed[j + 2];
        const float* ha = hb + (long)(pa >> 3) * 64;
        const float* hc = hb + (long)(pb >> 3) * 64;
        float a0 = ha[o], a1 = ha[32 + o];
        float b0 = hc[o], b1 = hc[32 + o];
        int ra = (pa & 7) * 2, rb = (pb & 7) * 2;
        acc = fmaf(sc[ra], a0, fmaf(sc[ra + 1], a1, acc));
        acc = fmaf(sc[rb], b0, fmaf(sc[rb + 1], b1, acc));
    }
    if (j < end) {
        unsigned pa = packed[j];
        const float* ha = hb + (long)(pa >> 3) * 64;
        int ra = (pa & 7) * 2;
        acc = fmaf(sc[ra], ha[o], fmaf(sc[ra + 1], ha[32 + o], acc));
    }
    acc += __shfl_xor(acc, 32);
    if (half == 0) {
        float* p = h0 + (long)n * 32 + o;
        *p = tanhf(*p + acc);
    }
}

// ---------------------------------------------------------------------------
// Layers 1/2 pull in INPUT space: u[n][b][i] = sum_e comb[r,b] * hsrc[s][i].
__global__ __launch_bounds__(256)
void k_pull_u(const int* __restrict__ rowptr, const unsigned* __restrict__ packed,
              const float* __restrict__ comb, const float* __restrict__ hsrc,
              float* __restrict__ u, int nNodes)
{
    __shared__ float sc[16];
    if (threadIdx.x < 16) sc[threadIdx.x] = comb[threadIdx.x];
    __syncthreads();
    int n = blockIdx.x * 4 + (threadIdx.x >> 6);
    if (n >= nNodes) return;
    int lane = threadIdx.x & 63, i = lane & 31, half = lane >> 5;
    int beg = rowptr[n], end = rowptr[n + 1];
    float u0 = 0.f, u1 = 0.f;
    int j = beg + half;
    for (; j + 2 < end; j += 4) {
        unsigned pa = packed[j], pb = packed[j + 2];
        float ha = hsrc[(long)(pa >> 3) * 32 + i];
        float hc = hsrc[(long)(pb >> 3) * 32 + i];
        int ra = (pa & 7) * 2, rb = (pb & 7) * 2;
        u0 = fmaf(sc[ra], ha, u0);  u1 = fmaf(sc[ra + 1], ha, u1);
        u0 = fmaf(sc[rb], hc, u0);  u1 = fmaf(sc[rb + 1], hc, u1);
    }
    if (j < end) {
        unsigned pa = packed[j];
        float ha = hsrc[(long)(pa >> 3) * 32 + i];
        int ra = (pa & 7) * 2;
        u0 = fmaf(sc[ra], ha, u0);  u1 = fmaf(sc[ra + 1], ha, u1);
    }
    u0 += __shfl_xor(u0, 32);
    u1 += __shfl_xor(u1, 32);
    if (half == 0) {
        u[(long)n * 64 + i]      = u0;
        u[(long)n * 64 + 32 + i] = u1;
    }
}

// ---------------------------------------------------------------------------
// Post GEMM for layers 1/2: hdst = tanh([u0|u1|hsrc] @ [V0;V1;loop] + bias).
__global__ __launch_bounds__(256, 2)
void k_post(const float* __restrict__ u, const float* __restrict__ hsrc,
            const float* __restrict__ V, const float* __restrict__ loopw,
            const float* __restrict__ bias, float* __restrict__ hdst, int nNodes)
{
    __shared__ float CW[96 * 32];
    for (int idx = threadIdx.x; idx < 96 * 32; idx += 256) {
        int i = idx / 32, o = idx % 32;
        CW[idx] = (i < 64) ? V[i * 32 + o]
                           : loopw[(i - 64) * 32 + o];
    }
    __syncthreads();

    const int cg = threadIdx.x & 7;
    const int ng = threadIdx.x >> 3;
    const int c0 = cg * 4;
    const int base = blockIdx.x * 128 + ng * 4;
    if (base >= nNodes) return;

    long rows[4];
    #pragma unroll
    for (int j = 0; j < 4; ++j)
        rows[j] = (long)min(base + j, nNodes - 1);

    float acc[4][4] = {};
    #pragma unroll 2
    for (int i = 0; i < 96; i += 4) {
        f4 w0 = *(const f4*)&CW[(i + 0) * 32 + c0];
        f4 w1 = *(const f4*)&CW[(i + 1) * 32 + c0];
        f4 w2 = *(const f4*)&CW[(i + 2) * 32 + c0];
        f4 w3 = *(const f4*)&CW[(i + 3) * 32 + c0];
        #pragma unroll
        for (int j = 0; j < 4; ++j) {
            f4 hv = (i < 64) ? *(const f4*)(u + rows[j] * 64 + i)
                             : *(const f4*)(hsrc + rows[j] * 32 + (i - 64));
            #pragma unroll
            for (int q = 0; q < 4; ++q)
                acc[j][q] = fmaf(hv[3], w3[q],
                            fmaf(hv[2], w2[q],
                            fmaf(hv[1], w1[q],
                            fmaf(hv[0], w0[q], acc[j][q]))));
        }
    }

    f4 bv = *(const f4*)(bias + c0);
    #pragma unroll
    for (int j = 0; j < 4; ++j)
        if (base + j < nNodes) {
            f4 v = {tanhf(acc[j][0] + bv[0]), tanhf(acc[j][1] + bv[1]),
                    tanhf(acc[j][2] + bv[2]), tanhf(acc[j][3] + bv[3])};
            *(f4*)(hdst + (long)(base + j) * 32 + c0) = v;
        }
}

// ---------------------------------------------------------------------------
// Fused MLP heads + reparameterization, register-tiled.
__global__ __launch_bounds__(256, 2)
void k_mlp(const float* __restrict__ h0, const float* __restrict__ h1,
           const float* __restrict__ h2,
           const float* __restrict__ Wm1, const float* __restrict__ bm1,
           const float* __restrict__ Wm2, const float* __restrict__ bm2,
           const float* __restrict__ Ws1, const float* __restrict__ bs1,
           const float* __restrict__ Ws2, const float* __restrict__ bs2,
           const float* __restrict__ noise, float* __restrict__ z, int nNodes)
{
    __shared__ float sW1[2][96 * 32];
    __shared__ float sW2[2][32 * 128];
    __shared__ float sb1[2][32];
    __shared__ float sb2[2][128];
    __shared__ float shid[2][64][32];

    for (int i = threadIdx.x; i < 96 * 32; i += 256) { sW1[0][i] = Wm1[i]; sW1[1][i] = Ws1[i]; }
    for (int i = threadIdx.x; i < 32 * 128; i += 256) { sW2[0][i] = Wm2[i]; sW2[1][i] = Ws2[i]; }
    if (threadIdx.x < 32)  { sb1[0][threadIdx.x] = bm1[threadIdx.x]; sb1[1][threadIdx.x] = bs1[threadIdx.x]; }
    if (threadIdx.x < 128) { sb2[0][threadIdx.x] = bm2[threadIdx.x]; sb2[1][threadIdx.x] = bs2[threadIdx.x]; }
    __syncthreads();

    const int base = blockIdx.x * 64;
    if (base >= nNodes) return;

    // ---- phase A: hidden = relu(cs @ W1 + b1) ----
    {
        const int head = threadIdx.x >> 7;
        const int rem  = threadIdx.x & 127;
        const int ng   = rem >> 3;
        const int c0   = (rem & 7) * 4;
        const float* sW = sW1[head];
        long rows[4];
        #pragma unroll
        for (int j = 0; j < 4; ++j)
            rows[j] = (long)min(base + ng * 4 + j, nNodes - 1);

        float acc[4][4] = {};
        const float* hs[3] = {h0, h1, h2};
        #pragma unroll
        for (int part = 0; part < 3; ++part) {
            const float* hp = hs[part];
            #pragma unroll
            for (int kk = 0; kk < 32; kk += 4) {
                const int k = part * 32 + kk;
                f4 w0 = *(const f4*)&sW[(k + 0) * 32 + c0];
                f4 w1 = *(const f4*)&sW[(k + 1) * 32 + c0];
                f4 w2 = *(const f4*)&sW[(k + 2) * 32 + c0];
                f4 w3 = *(const f4*)&sW[(k + 3) * 32 + c0];
                #pragma unroll
                for (int j = 0; j < 4; ++j) {
                    f4 hv = *(const f4*)(hp + rows[j] * 32 + kk);
                    #pragma unroll
                    for (int q = 0; q < 4; ++q)
                        acc[j][q] = fmaf(hv[3], w3[q],
                                    fmaf(hv[2], w2[q],
                                    fmaf(hv[1], w1[q],
                                    fmaf(hv[0], w0[q], acc[j][q]))));
                }
            }
        }
        f4 bv = *(const f4*)&sb1[head][c0];
        #pragma unroll
        for (int j = 0; j < 4; ++j) {
            f4 v = {fmaxf(acc[j][0] + bv[0], 0.f), fmaxf(acc[j][1] + bv[1], 0.f),
                    fmaxf(acc[j][2] + bv[2], 0.f), fmaxf(acc[j][3] + bv[3], 0.f)};
            *(f4*)&shid[head][ng * 4 + j][c0] = v;
        }
    }
    __syncthreads();

    // ---- phase B: out = hid @ W2 + b2; z = mean + noise * exp(log_std) ----
    const int ng = threadIdx.x >> 5;
    const int c0 = (threadIdx.x & 31) * 4;
    #pragma unroll
    for (int pass = 0; pass < 2; ++pass) {
        const int nb = pass * 32 + ng * 4;
        float am[4][4] = {}, as_[4][4] = {};
        #pragma unroll 4
        for (int k = 0; k < 32; k += 4) {
            f4 wm0 = *(const f4*)&sW2[0][(k + 0) * 128 + c0];
            f4 wm1 = *(const f4*)&sW2[0][(k + 1) * 128 + c0];
            f4 wm2 = *(const f4*)&sW2[0][(k + 2) * 128 + c0];
            f4 wm3 = *(const f4*)&sW2[0][(k + 3) * 128 + c0];
            f4 ws0 = *(const f4*)&sW2[1][(k + 0) * 128 + c0];
            f4 ws1 = *(const f4*)&sW2[1][(k + 1) * 128 + c0];
            f4 ws2 = *(const f4*)&sW2[1][(k + 2) * 128 + c0];
            f4 ws3 = *(const f4*)&sW2[1][(k + 3) * 128 + c0];
            #pragma unroll
            for (int j = 0; j < 4; ++j) {
                f4 hm = *(const f4*)&shid[0][nb + j][k];
                f4 hv = *(const f4*)&shid[1][nb + j][k];
                #pragma unroll
                for (int q = 0; q < 4; ++q) {
                    am[j][q]  = fmaf(hm[3], wm3[q],
                                fmaf(hm[2], wm2[q],
                                fmaf(hm[1], wm1[q],
                                fmaf(hm[0], wm0[q], am[j][q]))));
                    as_[j][q] = fmaf(hv[3], ws3[q],
                                fmaf(hv[2], ws2[q],
                                fmaf(hv[1], ws1[q],
                                fmaf(hv[0], ws0[q], as_[j][q]))));
                }
            }
        }
        f4 b2m = *(const f4*)&sb2[0][c0];
        f4 b2s = *(const f4*)&sb2[1][c0];
        #pragma unroll
        for (int j = 0; j < 4; ++j) {
            const int n = base + nb + j;
            if (n < nNodes) {
                f4 nz = *(const f4*)(noise + (long)n * 128 + c0);
                f4 v;
                #pragma unroll
                for (int q = 0; q < 4; ++q)
                    v[q] = fmaf(nz[q], expf(as_[j][q] + b2s[q]), am[j][q] + b2m[q]);
                *(f4*)(z + (long)n * 128 + c0) = v;
            }
        }
    }
}

// ---------------------------------------------------------------------------
__global__ __launch_bounds__(256)
void k_pairs(const float* __restrict__ z, const int* __restrict__ ui,
             const int* __restrict__ ii, float* __restrict__ out, int U, int T)
{
    int w = (blockIdx.x * 256 + threadIdx.x) >> 6;
    int lane = threadIdx.x & 63;
    if (w >= U) return;
    int a = ui[w], b = ii[w];
    float a0 = z[(long)a * 128 + lane], a1 = z[(long)a * 128 + 64 + lane];
    float b0 = z[(long)b * 128 + lane], b1 = z[(long)b * 128 + 64 + lane];
    float* res = out + U + T;
    res[(long)w * 128 + lane] = a0;
    res[(long)w * 128 + 64 + lane] = a1;
    res[(long)(U + w) * 128 + lane] = b0;
    res[(long)(U + w) * 128 + 64 + lane] = b1;
    float d = fmaf(a0, b0, a1 * b1);
    #pragma unroll
    for (int off = 32; off; off >>= 1) d += __shfl_xor(d, off);
    if (lane == 0) out[w] = d;
}

__global__ __launch_bounds__(256)
void k_preds(const float* __restrict__ z, const int* __restrict__ ts,
             const int* __restrict__ td, float* __restrict__ out, int U, int T)
{
    int w = (blockIdx.x * 256 + threadIdx.x) >> 6;
    int lane = threadIdx.x & 63;
    if (w >= T) return;
    int a = ts[w], b = td[w];
    float a0 = z[(long)a * 128 + lane], a1 = z[(long)a * 128 + 64 + lane];
    float b0 = z[(long)b * 128 + lane], b1 = z[(long)b * 128 + 64 + lane];
    float d = fmaf(a0, b0, a1 * b1);
    #pragma unroll
    for (int off = 32; off; off >>= 1) d += __shfl_xor(d, off);
    if (lane == 0) out[U + w] = d;
}

// ---------------------------------------------------------------------------
extern "C" void kernel_launch(void* const* d_in, const int* in_sizes, int n_in,
                              void* d_out, int out_size, void* d_ws, size_t ws_size,
                              hipStream_t stream)
{
    const float* x     = (const float*)d_in[0];
    const int*   src   = (const int*)d_in[1];
    const int*   dst   = (const int*)d_in[2];
    const int*   et    = (const int*)d_in[3];
    const float* noise = (const float*)d_in[4];
    const int*   ui    = (const int*)d_in[5];
    const int*   ii    = (const int*)d_in[6];
    const int*   tes   = (const int*)d_in[7];
    const int*   ted   = (const int*)d_in[8];
    const float* V0    = (const float*)d_in[9];
    const float* comb0 = (const float*)d_in[10];
    const float* loop0 = (const float*)d_in[11];
    const float* b0    = (const float*)d_in[12];
    const float* V1    = (const float*)d_in[13];
    const float* comb1 = (const float*)d_in[14];
    const float* loop1 = (const float*)d_in[15];
    const float* b1    = (const float*)d_in[16];
    const float* V2    = (const float*)d_in[17];
    const float* comb2 = (const float*)d_in[18];
    const float* loop2 = (const float*)d_in[19];
    const float* b2    = (const float*)d_in[20];
    const float* Wm1   = (const float*)d_in[21];
    const float* bm1   = (const float*)d_in[22];
    const float* Wm2   = (const float*)d_in[23];
    const float* bm2   = (const float*)d_in[24];
    const float* Ws1   = (const float*)d_in[25];
    const float* bs1   = (const float*)d_in[26];
    const float* Ws2   = (const float*)d_in[27];
    const float* bs2   = (const float*)d_in[28];

    const int N = in_sizes[0] / 128;   // 200000
    const int E = in_sizes[1];         // 3200000
    const int U = in_sizes[5];
    const int T = in_sizes[7];
    const int NB = (N + 255) / 256;    // 782 buckets
    const int chunk = (E + NBLK - 1) / NBLK;

    float* out = (float*)d_out;

    // Workspace (floats): hb/u[N*64] | h0[N*32] | h1 | h2 | z[N*128]
    // CSR scratch aliases the z region (dead before k_mlp writes z):
    //   rowptr[N+1] | packed[E] | bpk[E] | hist[NBLK*MAXB] | base[NBLK*MAXB]
    //   | colsum[NB] | bb[NB+1]
    float* ws = (float*)d_ws;
    float* hb = ws;
    float* h0 = hb + (long)N * 64;
    float* h1 = h0 + (long)N * 32;
    float* h2 = h1 + (long)N * 32;
    float* z  = h2 + (long)N * 32;
    int*      rowptr = (int*)z;
    unsigned* packed = (unsigned*)(rowptr + N + 1);
    unsigned* bpk    = packed + E;
    int*      hist   = (int*)(bpk + E);
    int*      basep  = hist + NBLK * MAXB;
    int*      colsum = basep + NBLK * MAXB;
    int*      bb     = colsum + NB;

    const int hbBlocks   = (N + 63) / 64;
    const int pullBlocks = (N + 3) / 4;
    const int postBlocks = (N + 127) / 128;
    const int mlpBlocks  = (N + 63) / 64;

    // ---- contention-free bucketed CSR build (by dst) ----
    k_bhist2<<<NBLK, 256, 0, stream>>>(dst, hist, E, NB, chunk);
    k_colscan<<<NB, 256, 0, stream>>>(hist, basep, colsum, NB);
    k_bscan2<<<1, 1024, 0, stream>>>(colsum, bb, rowptr, NB, N, E);
    k_bscatter2<<<NBLK, 256, 0, stream>>>(src, dst, et, basep, bb, bpk, E, NB, chunk);
    k_bucket<<<NB, 256, 0, stream>>>(bpk, bb, rowptr, packed, N);

    // ---- layer 0 ----
    k_hb<128><<<hbBlocks, 384, 0, stream>>>(x, V0, loop0, b0, hb, h0, N);
    k_pull0<<<pullBlocks, 256, 0, stream>>>(rowptr, packed, comb0, hb, h0, N);

    // ---- layer 1 ----
    k_pull_u<<<pullBlocks, 256, 0, stream>>>(rowptr, packed, comb1, h0, hb, N);
    k_post<<<postBlocks, 256, 0, stream>>>(hb, h0, V1, loop1, b1, h1, N);

    // ---- layer 2 ----
    k_pull_u<<<pullBlocks, 256, 0, stream>>>(rowptr, packed, comb2, h1, hb, N);
    k_post<<<postBlocks, 256, 0, stream>>>(hb, h1, V2, loop2, b2, h2, N);

    // ---- heads + reparameterization ----
    k_mlp<<<mlpBlocks, 256, 0, stream>>>(h0, h1, h2, Wm1, bm1, Wm2, bm2,
                                         Ws1, bs1, Ws2, bs2, noise, z, N);
    // ---- outputs ----
    k_pairs<<<(U * 64 + 255) / 256, 256, 0, stream>>>(z, ui, ii, out, U, T);
    k_preds<<<(T * 64 + 255) / 256, 256, 0, stream>>>(z, tes, ted, out, U, T);
}

// Round 7
// 911.930 us; speedup vs baseline: 1.7997x; 1.0399x over previous
//
#include <hip/hip_runtime.h>
#include <hip/hip_bf16.h>

// N=200000, E=3200000, R=8, B=2, IN=128, H=32, OUT=128, U=10000, T=50000.

typedef float f4 __attribute__((ext_vector_type(4)));
typedef unsigned short u16;
typedef u16 us4 __attribute__((ext_vector_type(4)));   // 4 bf16 = 8 bytes

__device__ inline u16 f2b(float f) {
    __hip_bfloat16 h = __float2bfloat16(f);
    return __builtin_bit_cast(u16, h);
}
__device__ inline float b2f(u16 s) {
    return __bfloat162float(__builtin_bit_cast(__hip_bfloat16, s));
}
__device__ inline f4 b4f(us4 v) {
    f4 r = {b2f(v.x), b2f(v.y), b2f(v.z), b2f(v.w)};
    return r;
}

#define NBLK 256      // scatter blocks
#define MAXB 800      // >= NB = ceil(N/256) = 782

// ---------------------------------------------------------------------------
// Layer-0 basis projection + self-loop GEMM: [N x 128] @ [128 x 96].
// cols 0..63 -> hb (bf16); cols 64..95 -> h0 = x@loop + bias (bf16, agg init).
// 192 threads = 8 node-groups x 24 col-groups; 8 nodes/thread -> 64/block.
// launch_bounds(192,2): no tight VGPR cap (round-5's (384,4)->44 VGPR was a
// 20% regression; the loop needs ~100 live regs for 32 acc + loads in flight).
template<int DIN>
__global__ __launch_bounds__(192, 2)
void k_hb(const float* __restrict__ h, const float* __restrict__ V,
          const float* __restrict__ loopw, const float* __restrict__ bias,
          u16* __restrict__ hb, u16* __restrict__ agg, int nNodes)
{
    __shared__ float CW[DIN * 96];
    for (int idx = threadIdx.x; idx < DIN * 96; idx += 192) {
        int i = idx / 96, c = idx % 96;
        CW[idx] = (c < 64) ? V[(c >> 5) * DIN * 32 + i * 32 + (c & 31)]
                           : loopw[i * 32 + (c - 64)];
    }
    __syncthreads();

    const int cg = threadIdx.x % 24;
    const int ng = threadIdx.x / 24;
    const int c0 = cg * 4;
    const int base = blockIdx.x * 64 + ng * 8;
    if (base >= nNodes) return;

    long rows[8];
    #pragma unroll
    for (int j = 0; j < 8; ++j)
        rows[j] = (long)min(base + j, nNodes - 1);

    float acc[8][4] = {};
    for (int i = 0; i < DIN; i += 4) {
        f4 w0 = *(const f4*)&CW[(i + 0) * 96 + c0];
        f4 w1 = *(const f4*)&CW[(i + 1) * 96 + c0];
        f4 w2 = *(const f4*)&CW[(i + 2) * 96 + c0];
        f4 w3 = *(const f4*)&CW[(i + 3) * 96 + c0];
        #pragma unroll
        for (int j = 0; j < 8; ++j) {
            f4 hv = *(const f4*)(h + rows[j] * DIN + i);
            #pragma unroll
            for (int q = 0; q < 4; ++q)
                acc[j][q] = fmaf(hv[3], w3[q],
                            fmaf(hv[2], w2[q],
                            fmaf(hv[1], w1[q],
                            fmaf(hv[0], w0[q], acc[j][q]))));
        }
    }

    if (c0 < 64) {
        #pragma unroll
        for (int j = 0; j < 8; ++j)
            if (base + j < nNodes) {
                us4 v = {f2b(acc[j][0]), f2b(acc[j][1]),
                         f2b(acc[j][2]), f2b(acc[j][3])};
                *(us4*)(hb + (long)(base + j) * 64 + c0) = v;
            }
    } else {
        f4 bv = *(const f4*)(bias + (c0 - 64));
        #pragma unroll
        for (int j = 0; j < 8; ++j)
            if (base + j < nNodes) {
                us4 v = {f2b(acc[j][0] + bv[0]), f2b(acc[j][1] + bv[1]),
                         f2b(acc[j][2] + bv[2]), f2b(acc[j][3] + bv[3])};
                *(us4*)(agg + (long)(base + j) * 32 + (c0 - 64)) = v;
            }
    }
}

// ---------------------------------------------------------------------------
// Contention-free bucketed CSR build (unchanged from round 6).
__global__ __launch_bounds__(256)
void k_bhist2(const int* __restrict__ dst, int* __restrict__ hist,
              int nEdges, int nB, int chunk)
{
    __shared__ int hloc[MAXB];
    for (int i = threadIdx.x; i < nB; i += 256) hloc[i] = 0;
    __syncthreads();
    const int ebeg = blockIdx.x * chunk;
    const int eend = min(ebeg + chunk, nEdges);
    for (int e = ebeg + threadIdx.x; e < eend; e += 256)
        atomicAdd(&hloc[dst[e] >> 8], 1);
    __syncthreads();
    for (int i = threadIdx.x; i < nB; i += 256)
        hist[blockIdx.x * MAXB + i] = hloc[i];
}

__global__ __launch_bounds__(256)
void k_colscan(const int* __restrict__ hist, int* __restrict__ base,
               int* __restrict__ colsum, int nB)
{
    __shared__ int s[256];
    const int b = blockIdx.x;
    const int t = threadIdx.x;
    int v = hist[t * MAXB + b];
    s[t] = v; __syncthreads();
    for (int off = 1; off < 256; off <<= 1) {
        int tmp = (t >= off) ? s[t - off] : 0;
        __syncthreads();
        s[t] += tmp;
        __syncthreads();
    }
    base[t * MAXB + b] = s[t] - v;
    if (t == 255) colsum[b] = s[255];
}

__global__ __launch_bounds__(1024)
void k_bscan2(const int* __restrict__ colsum, int* __restrict__ bb,
              int* __restrict__ rowptr, int nB, int nNodes, int nEdges)
{
    __shared__ int s[1024];
    int t = threadIdx.x;
    int v = (t < nB) ? colsum[t] : 0;
    s[t] = v; __syncthreads();
    for (int off = 1; off < 1024; off <<= 1) {
        int tmp = (t >= off) ? s[t - off] : 0;
        __syncthreads();
        s[t] += tmp;
        __syncthreads();
    }
    if (t < nB) bb[t] = s[t] - v;
    if (t == 0) { bb[nB] = nEdges; rowptr[nNodes] = nEdges; }
}

__global__ __launch_bounds__(256)
void k_bscatter2(const int* __restrict__ src, const int* __restrict__ dst,
                 const int* __restrict__ et, const int* __restrict__ base,
                 const int* __restrict__ bb, unsigned* __restrict__ bpk,
                 int nEdges, int nB, int chunk)
{
    __shared__ int sbase[MAXB];
    __shared__ int cur[MAXB];
    for (int i = threadIdx.x; i < nB; i += 256) {
        sbase[i] = bb[i] + base[blockIdx.x * MAXB + i];
        cur[i] = 0;
    }
    __syncthreads();
    const int ebeg = blockIdx.x * chunk;
    const int eend = min(ebeg + chunk, nEdges);
    for (int e = ebeg + threadIdx.x; e < eend; e += 256) {
        int d = dst[e];
        int b = d >> 8;
        int r = atomicAdd(&cur[b], 1);
        bpk[sbase[b] + r] = ((unsigned)(d & 255) << 21)
                          | ((unsigned)src[e] << 3) | (unsigned)et[e];
    }
}

__global__ __launch_bounds__(256)
void k_bucket(const unsigned* __restrict__ bpk, const int* __restrict__ bbase,
              int* __restrict__ rowptr, unsigned* __restrict__ packed, int nNodes)
{
    __shared__ int s[256];
    __shared__ int cur[256];
    const int b = blockIdx.x;
    const int t = threadIdx.x;
    const int ebeg = bbase[b], eend = bbase[b + 1];

    cur[t] = 0;
    __syncthreads();
    for (int j = ebeg + t; j < eend; j += 256)
        atomicAdd(&cur[bpk[j] >> 21], 1);
    __syncthreads();
    int v = cur[t];
    s[t] = v; __syncthreads();
    for (int off = 1; off < 256; off <<= 1) {
        int tmp = (t >= off) ? s[t - off] : 0;
        __syncthreads();
        s[t] += tmp;
        __syncthreads();
    }
    int ex = s[t] - v;
    int node = b * 256 + t;
    if (node < nNodes) rowptr[node] = ebeg + ex;
    cur[t] = ex;
    __syncthreads();
    for (int j = ebeg + t; j < eend; j += 256) {
        unsigned p = bpk[j];
        int pos = ebeg + atomicAdd(&cur[p >> 21], 1);
        packed[pos] = p & 0x1FFFFFu;
    }
}

// ---------------------------------------------------------------------------
// Layer-0 pull (bf16 hb gather, 128B/edge instead of 256B).
__global__ __launch_bounds__(256)
void k_pull0(const int* __restrict__ rowptr, const unsigned* __restrict__ packed,
             const float* __restrict__ comb, const u16* __restrict__ hb,
             u16* __restrict__ h0, int nNodes)
{
    __shared__ float sc[16];
    if (threadIdx.x < 16) sc[threadIdx.x] = comb[threadIdx.x];
    __syncthreads();
    int n = blockIdx.x * 4 + (threadIdx.x >> 6);
    if (n >= nNodes) return;
    int lane = threadIdx.x & 63, o = lane & 31, half = lane >> 5;
    int beg = rowptr[n], end = rowptr[n + 1];
    float acc = 0.f;
    int j = beg + half;
    for (; j + 2 < end; j += 4) {
        unsigned pa = packed[j], pb = packed[j + 2];
        const u16* ha = hb + (long)(pa >> 3) * 64;
        const u16* hc = hb + (long)(pb >> 3) * 64;
        float a0 = b2f(ha[o]), a1 = b2f(ha[32 + o]);
        float b0 = b2f(hc[o]), b1 = b2f(hc[32 + o]);
        int ra = (pa & 7) * 2, rb = (pb & 7) * 2;
        acc = fmaf(sc[ra], a0, fmaf(sc[ra + 1], a1, acc));
        acc = fmaf(sc[rb], b0, fmaf(sc[rb + 1], b1, acc));
    }
    if (j < end) {
        unsigned pa = packed[j];
        const u16* ha = hb + (long)(pa >> 3) * 64;
        int ra = (pa & 7) * 2;
        acc = fmaf(sc[ra], b2f(ha[o]), fmaf(sc[ra + 1], b2f(ha[32 + o]), acc));
    }
    acc += __shfl_xor(acc, 32);
    if (half == 0) {
        long idx = (long)n * 32 + o;
        h0[idx] = f2b(tanhf(b2f(h0[idx]) + acc));
    }
}

// ---------------------------------------------------------------------------
// Layers 1/2 pull in INPUT space (bf16 hsrc gather, 64B/edge).
__global__ __launch_bounds__(256)
void k_pull_u(const int* __restrict__ rowptr, const unsigned* __restrict__ packed,
              const float* __restrict__ comb, const u16* __restrict__ hsrc,
              float* __restrict__ u, int nNodes)
{
    __shared__ float sc[16];
    if (threadIdx.x < 16) sc[threadIdx.x] = comb[threadIdx.x];
    __syncthreads();
    int n = blockIdx.x * 4 + (threadIdx.x >> 6);
    if (n >= nNodes) return;
    int lane = threadIdx.x & 63, i = lane & 31, half = lane >> 5;
    int beg = rowptr[n], end = rowptr[n + 1];
    float u0 = 0.f, u1 = 0.f;
    int j = beg + half;
    for (; j + 2 < end; j += 4) {
        unsigned pa = packed[j], pb = packed[j + 2];
        float ha = b2f(hsrc[(long)(pa >> 3) * 32 + i]);
        float hc = b2f(hsrc[(long)(pb >> 3) * 32 + i]);
        int ra = (pa & 7) * 2, rb = (pb & 7) * 2;
        u0 = fmaf(sc[ra], ha, u0);  u1 = fmaf(sc[ra + 1], ha, u1);
        u0 = fmaf(sc[rb], hc, u0);  u1 = fmaf(sc[rb + 1], hc, u1);
    }
    if (j < end) {
        unsigned pa = packed[j];
        float ha = b2f(hsrc[(long)(pa >> 3) * 32 + i]);
        int ra = (pa & 7) * 2;
        u0 = fmaf(sc[ra], ha, u0);  u1 = fmaf(sc[ra + 1], ha, u1);
    }
    u0 += __shfl_xor(u0, 32);
    u1 += __shfl_xor(u1, 32);
    if (half == 0) {
        u[(long)n * 64 + i]      = u0;
        u[(long)n * 64 + 32 + i] = u1;
    }
}

// ---------------------------------------------------------------------------
// Post GEMM for layers 1/2: hdst = tanh([u0|u1|hsrc] @ [V0;V1;loop] + bias).
// u is f32, hsrc/hdst bf16.
__global__ __launch_bounds__(256, 2)
void k_post(const float* __restrict__ u, const u16* __restrict__ hsrc,
            const float* __restrict__ V, const float* __restrict__ loopw,
            const float* __restrict__ bias, u16* __restrict__ hdst, int nNodes)
{
    __shared__ float CW[96 * 32];
    for (int idx = threadIdx.x; idx < 96 * 32; idx += 256) {
        int i = idx / 32, o = idx % 32;
        CW[idx] = (i < 64) ? V[i * 32 + o]
                           : loopw[(i - 64) * 32 + o];
    }
    __syncthreads();

    const int cg = threadIdx.x & 7;
    const int ng = threadIdx.x >> 3;
    const int c0 = cg * 4;
    const int base = blockIdx.x * 128 + ng * 4;
    if (base >= nNodes) return;

    long rows[4];
    #pragma unroll
    for (int j = 0; j < 4; ++j)
        rows[j] = (long)min(base + j, nNodes - 1);

    float acc[4][4] = {};
    #pragma unroll 2
    for (int i = 0; i < 96; i += 4) {
        f4 w0 = *(const f4*)&CW[(i + 0) * 32 + c0];
        f4 w1 = *(const f4*)&CW[(i + 1) * 32 + c0];
        f4 w2 = *(const f4*)&CW[(i + 2) * 32 + c0];
        f4 w3 = *(const f4*)&CW[(i + 3) * 32 + c0];
        #pragma unroll
        for (int j = 0; j < 4; ++j) {
            f4 hv;
            if (i < 64) hv = *(const f4*)(u + rows[j] * 64 + i);
            else        hv = b4f(*(const us4*)(hsrc + rows[j] * 32 + (i - 64)));
            #pragma unroll
            for (int q = 0; q < 4; ++q)
                acc[j][q] = fmaf(hv[3], w3[q],
                            fmaf(hv[2], w2[q],
                            fmaf(hv[1], w1[q],
                            fmaf(hv[0], w0[q], acc[j][q]))));
        }
    }

    f4 bv = *(const f4*)(bias + c0);
    #pragma unroll
    for (int j = 0; j < 4; ++j)
        if (base + j < nNodes) {
            us4 v = {f2b(tanhf(acc[j][0] + bv[0])), f2b(tanhf(acc[j][1] + bv[1])),
                     f2b(tanhf(acc[j][2] + bv[2])), f2b(tanhf(acc[j][3] + bv[3]))};
            *(us4*)(hdst + (long)(base + j) * 32 + c0) = v;
        }
}

// ---------------------------------------------------------------------------
// Fused MLP heads + reparameterization (bf16 h inputs, f32 z out).
__global__ __launch_bounds__(256, 2)
void k_mlp(const u16* __restrict__ h0, const u16* __restrict__ h1,
           const u16* __restrict__ h2,
           const float* __restrict__ Wm1, const float* __restrict__ bm1,
           const float* __restrict__ Wm2, const float* __restrict__ bm2,
           const float* __restrict__ Ws1, const float* __restrict__ bs1,
           const float* __restrict__ Ws2, const float* __restrict__ bs2,
           const float* __restrict__ noise, float* __restrict__ z, int nNodes)
{
    __shared__ float sW1[2][96 * 32];
    __shared__ float sW2[2][32 * 128];
    __shared__ float sb1[2][32];
    __shared__ float sb2[2][128];
    __shared__ float shid[2][64][32];

    for (int i = threadIdx.x; i < 96 * 32; i += 256) { sW1[0][i] = Wm1[i]; sW1[1][i] = Ws1[i]; }
    for (int i = threadIdx.x; i < 32 * 128; i += 256) { sW2[0][i] = Wm2[i]; sW2[1][i] = Ws2[i]; }
    if (threadIdx.x < 32)  { sb1[0][threadIdx.x] = bm1[threadIdx.x]; sb1[1][threadIdx.x] = bs1[threadIdx.x]; }
    if (threadIdx.x < 128) { sb2[0][threadIdx.x] = bm2[threadIdx.x]; sb2[1][threadIdx.x] = bs2[threadIdx.x]; }
    __syncthreads();

    const int base = blockIdx.x * 64;
    if (base >= nNodes) return;

    // ---- phase A: hidden = relu(cs @ W1 + b1) ----
    {
        const int head = threadIdx.x >> 7;
        const int rem  = threadIdx.x & 127;
        const int ng   = rem >> 3;
        const int c0   = (rem & 7) * 4;
        const float* sW = sW1[head];
        long rows[4];
        #pragma unroll
        for (int j = 0; j < 4; ++j)
            rows[j] = (long)min(base + ng * 4 + j, nNodes - 1);

        float acc[4][4] = {};
        const u16* hs[3] = {h0, h1, h2};
        #pragma unroll
        for (int part = 0; part < 3; ++part) {
            const u16* hp = hs[part];
            #pragma unroll
            for (int kk = 0; kk < 32; kk += 4) {
                const int k = part * 32 + kk;
                f4 w0 = *(const f4*)&sW[(k + 0) * 32 + c0];
                f4 w1 = *(const f4*)&sW[(k + 1) * 32 + c0];
                f4 w2 = *(const f4*)&sW[(k + 2) * 32 + c0];
                f4 w3 = *(const f4*)&sW[(k + 3) * 32 + c0];
                #pragma unroll
                for (int j = 0; j < 4; ++j) {
                    f4 hv = b4f(*(const us4*)(hp + rows[j] * 32 + kk));
                    #pragma unroll
                    for (int q = 0; q < 4; ++q)
                        acc[j][q] = fmaf(hv[3], w3[q],
                                    fmaf(hv[2], w2[q],
                                    fmaf(hv[1], w1[q],
                                    fmaf(hv[0], w0[q], acc[j][q]))));
                }
            }
        }
        f4 bv = *(const f4*)&sb1[head][c0];
        #pragma unroll
        for (int j = 0; j < 4; ++j) {
            f4 v = {fmaxf(acc[j][0] + bv[0], 0.f), fmaxf(acc[j][1] + bv[1], 0.f),
                    fmaxf(acc[j][2] + bv[2], 0.f), fmaxf(acc[j][3] + bv[3], 0.f)};
            *(f4*)&shid[head][ng * 4 + j][c0] = v;
        }
    }
    __syncthreads();

    // ---- phase B: out = hid @ W2 + b2; z = mean + noise * exp(log_std) ----
    const int ng = threadIdx.x >> 5;
    const int c0 = (threadIdx.x & 31) * 4;
    #pragma unroll
    for (int pass = 0; pass < 2; ++pass) {
        const int nb = pass * 32 + ng * 4;
        float am[4][4] = {}, as_[4][4] = {};
        #pragma unroll 4
        for (int k = 0; k < 32; k += 4) {
            f4 wm0 = *(const f4*)&sW2[0][(k + 0) * 128 + c0];
            f4 wm1 = *(const f4*)&sW2[0][(k + 1) * 128 + c0];
            f4 wm2 = *(const f4*)&sW2[0][(k + 2) * 128 + c0];
            f4 wm3 = *(const f4*)&sW2[0][(k + 3) * 128 + c0];
            f4 ws0 = *(const f4*)&sW2[1][(k + 0) * 128 + c0];
            f4 ws1 = *(const f4*)&sW2[1][(k + 1) * 128 + c0];
            f4 ws2 = *(const f4*)&sW2[1][(k + 2) * 128 + c0];
            f4 ws3 = *(const f4*)&sW2[1][(k + 3) * 128 + c0];
            #pragma unroll
            for (int j = 0; j < 4; ++j) {
                f4 hm = *(const f4*)&shid[0][nb + j][k];
                f4 hv = *(const f4*)&shid[1][nb + j][k];
                #pragma unroll
                for (int q = 0; q < 4; ++q) {
                    am[j][q]  = fmaf(hm[3], wm3[q],
                                fmaf(hm[2], wm2[q],
                                fmaf(hm[1], wm1[q],
                                fmaf(hm[0], wm0[q], am[j][q]))));
                    as_[j][q] = fmaf(hv[3], ws3[q],
                                fmaf(hv[2], ws2[q],
                                fmaf(hv[1], ws1[q],
                                fmaf(hv[0], ws0[q], as_[j][q]))));
                }
            }
        }
        f4 b2m = *(const f4*)&sb2[0][c0];
        f4 b2s = *(const f4*)&sb2[1][c0];
        #pragma unroll
        for (int j = 0; j < 4; ++j) {
            const int n = base + nb + j;
            if (n < nNodes) {
                f4 nz = *(const f4*)(noise + (long)n * 128 + c0);
                f4 v;
                #pragma unroll
                for (int q = 0; q < 4; ++q)
                    v[q] = fmaf(nz[q], expf(as_[j][q] + b2s[q]), am[j][q] + b2m[q]);
                *(f4*)(z + (long)n * 128 + c0) = v;
            }
        }
    }
}

// ---------------------------------------------------------------------------
__global__ __launch_bounds__(256)
void k_pairs(const float* __restrict__ z, const int* __restrict__ ui,
             const int* __restrict__ ii, float* __restrict__ out, int U, int T)
{
    int w = (blockIdx.x * 256 + threadIdx.x) >> 6;
    int lane = threadIdx.x & 63;
    if (w >= U) return;
    int a = ui[w], b = ii[w];
    float a0 = z[(long)a * 128 + lane], a1 = z[(long)a * 128 + 64 + lane];
    float b0 = z[(long)b * 128 + lane], b1 = z[(long)b * 128 + 64 + lane];
    float* res = out + U + T;
    res[(long)w * 128 + lane] = a0;
    res[(long)w * 128 + 64 + lane] = a1;
    res[(long)(U + w) * 128 + lane] = b0;
    res[(long)(U + w) * 128 + 64 + lane] = b1;
    float d = fmaf(a0, b0, a1 * b1);
    #pragma unroll
    for (int off = 32; off; off >>= 1) d += __shfl_xor(d, off);
    if (lane == 0) out[w] = d;
}

__global__ __launch_bounds__(256)
void k_preds(const float* __restrict__ z, const int* __restrict__ ts,
             const int* __restrict__ td, float* __restrict__ out, int U, int T)
{
    int w = (blockIdx.x * 256 + threadIdx.x) >> 6;
    int lane = threadIdx.x & 63;
    if (w >= T) return;
    int a = ts[w], b = td[w];
    float a0 = z[(long)a * 128 + lane], a1 = z[(long)a * 128 + 64 + lane];
    float b0 = z[(long)b * 128 + lane], b1 = z[(long)b * 128 + 64 + lane];
    float d = fmaf(a0, b0, a1 * b1);
    #pragma unroll
    for (int off = 32; off; off >>= 1) d += __shfl_xor(d, off);
    if (lane == 0) out[U + w] = d;
}

// ---------------------------------------------------------------------------
extern "C" void kernel_launch(void* const* d_in, const int* in_sizes, int n_in,
                              void* d_out, int out_size, void* d_ws, size_t ws_size,
                              hipStream_t stream)
{
    const float* x     = (const float*)d_in[0];
    const int*   src   = (const int*)d_in[1];
    const int*   dst   = (const int*)d_in[2];
    const int*   et    = (const int*)d_in[3];
    const float* noise = (const float*)d_in[4];
    const int*   ui    = (const int*)d_in[5];
    const int*   ii    = (const int*)d_in[6];
    const int*   tes   = (const int*)d_in[7];
    const int*   ted   = (const int*)d_in[8];
    const float* V0    = (const float*)d_in[9];
    const float* comb0 = (const float*)d_in[10];
    const float* loop0 = (const float*)d_in[11];
    const float* b0    = (const float*)d_in[12];
    const float* V1    = (const float*)d_in[13];
    const float* comb1 = (const float*)d_in[14];
    const float* loop1 = (const float*)d_in[15];
    const float* b1    = (const float*)d_in[16];
    const float* V2    = (const float*)d_in[17];
    const float* comb2 = (const float*)d_in[18];
    const float* loop2 = (const float*)d_in[19];
    const float* b2    = (const float*)d_in[20];
    const float* Wm1   = (const float*)d_in[21];
    const float* bm1   = (const float*)d_in[22];
    const float* Wm2   = (const float*)d_in[23];
    const float* bm2   = (const float*)d_in[24];
    const float* Ws1   = (const float*)d_in[25];
    const float* bs1   = (const float*)d_in[26];
    const float* Ws2   = (const float*)d_in[27];
    const float* bs2   = (const float*)d_in[28];

    const int N = in_sizes[0] / 128;   // 200000
    const int E = in_sizes[1];         // 3200000
    const int U = in_sizes[5];
    const int T = in_sizes[7];
    const int NB = (N + 255) / 256;    // 782 buckets
    const int chunk = (E + NBLK - 1) / NBLK;

    float* out = (float*)d_out;

    // Workspace layout (bytes):
    //  hb  bf16 [N][64]   25.6MB
    //  h0/h1/h2 bf16 [N][32] 12.8MB each
    //  u   f32 [N][64]    51.2MB
    //  z   f32 [N][128]  102.4MB  (CSR int scratch aliases z; dead by k_mlp)
    char* W = (char*)d_ws;
    u16*   hb = (u16*)W;
    u16*   h0 = (u16*)(W + (size_t)N * 64 * 2);
    u16*   h1 = h0 + (size_t)N * 32;
    u16*   h2 = h1 + (size_t)N * 32;
    float* u  = (float*)(W + (size_t)N * 64 * 2 + (size_t)N * 32 * 2 * 3);
    float* z  = u + (size_t)N * 64;

    int*      rowptr = (int*)z;
    unsigned* packed = (unsigned*)(rowptr + N + 1);
    unsigned* bpk    = packed + E;
    int*      hist   = (int*)(bpk + E);
    int*      basep  = hist + NBLK * MAXB;
    int*      colsum = basep + NBLK * MAXB;
    int*      bb     = colsum + NB;

    const int hbBlocks   = (N + 63) / 64;
    const int pullBlocks = (N + 3) / 4;
    const int postBlocks = (N + 127) / 128;
    const int mlpBlocks  = (N + 63) / 64;

    // ---- contention-free bucketed CSR build (by dst) ----
    k_bhist2<<<NBLK, 256, 0, stream>>>(dst, hist, E, NB, chunk);
    k_colscan<<<NB, 256, 0, stream>>>(hist, basep, colsum, NB);
    k_bscan2<<<1, 1024, 0, stream>>>(colsum, bb, rowptr, NB, N, E);
    k_bscatter2<<<NBLK, 256, 0, stream>>>(src, dst, et, basep, bb, bpk, E, NB, chunk);
    k_bucket<<<NB, 256, 0, stream>>>(bpk, bb, rowptr, packed, N);

    // ---- layer 0 ----
    k_hb<128><<<hbBlocks, 192, 0, stream>>>(x, V0, loop0, b0, hb, h0, N);
    k_pull0<<<pullBlocks, 256, 0, stream>>>(rowptr, packed, comb0, hb, h0, N);

    // ---- layer 1 ----
    k_pull_u<<<pullBlocks, 256, 0, stream>>>(rowptr, packed, comb1, h0, u, N);
    k_post<<<postBlocks, 256, 0, stream>>>(u, h0, V1, loop1, b1, h1, N);

    // ---- layer 2 ----
    k_pull_u<<<pullBlocks, 256, 0, stream>>>(rowptr, packed, comb2, h1, u, N);
    k_post<<<postBlocks, 256, 0, stream>>>(u, h1, V2, loop2, b2, h2, N);

    // ---- heads + reparameterization ----
    k_mlp<<<mlpBlocks, 256, 0, stream>>>(h0, h1, h2, Wm1, bm1, Wm2, bm2,
                                         Ws1, bs1, Ws2, bs2, noise, z, N);
    // ---- outputs ----
    k_pairs<<<(U * 64 + 255) / 256, 256, 0, stream>>>(z, ui, ii, out, U, T);
    k_preds<<<(T * 64 + 255) / 256, 256, 0, stream>>>(z, tes, ted, out, U, T);
}

// Round 8
// 786.806 us; speedup vs baseline: 2.0859x; 1.1590x over previous
//
#include <hip/hip_runtime.h>
#include <hip/hip_bf16.h>

// N=200000, E=3200000, R=8, B=2, IN=128, H=32, OUT=128, U=10000, T=50000.

typedef float f4 __attribute__((ext_vector_type(4)));
typedef unsigned short u16;
typedef u16 us4 __attribute__((ext_vector_type(4)));   // 4 bf16 = 8 bytes

__device__ inline u16 f2b(float f) {
    __hip_bfloat16 h = __float2bfloat16(f);
    return __builtin_bit_cast(u16, h);
}
__device__ inline float b2f(u16 s) {
    return __bfloat162float(__builtin_bit_cast(__hip_bfloat16, s));
}
__device__ inline f4 b4f(us4 v) {
    f4 r = {b2f(v.x), b2f(v.y), b2f(v.z), b2f(v.w)};
    return r;
}

#define NBLK 256      // scatter blocks
#define MAXB 800      // >= NB = ceil(N/256) = 782

// ---------------------------------------------------------------------------
// Layer-0 basis projection + self-loop GEMM: [N x 128] @ [128 x 96].
// Weight tile in LDS as bf16 (24KB vs 48KB f32) -> ~6 blocks/CU instead of 2.
// Cvt overhead: 16 cvts per 128 FMAs. 192 thr = 8 node-grp x 24 col-grp.
template<int DIN>
__global__ __launch_bounds__(192, 2)
void k_hb(const float* __restrict__ h, const float* __restrict__ V,
          const float* __restrict__ loopw, const float* __restrict__ bias,
          u16* __restrict__ hb, u16* __restrict__ agg, int nNodes)
{
    __shared__ u16 CW[DIN * 96];
    for (int idx = threadIdx.x; idx < DIN * 96; idx += 192) {
        int i = idx / 96, c = idx % 96;
        float w = (c < 64) ? V[(c >> 5) * DIN * 32 + i * 32 + (c & 31)]
                           : loopw[i * 32 + (c - 64)];
        CW[idx] = f2b(w);
    }
    __syncthreads();

    const int cg = threadIdx.x % 24;
    const int ng = threadIdx.x / 24;
    const int c0 = cg * 4;
    const int base = blockIdx.x * 64 + ng * 8;
    if (base >= nNodes) return;

    long rows[8];
    #pragma unroll
    for (int j = 0; j < 8; ++j)
        rows[j] = (long)min(base + j, nNodes - 1);

    float acc[8][4] = {};
    for (int i = 0; i < DIN; i += 4) {
        f4 w0 = b4f(*(const us4*)&CW[(i + 0) * 96 + c0]);
        f4 w1 = b4f(*(const us4*)&CW[(i + 1) * 96 + c0]);
        f4 w2 = b4f(*(const us4*)&CW[(i + 2) * 96 + c0]);
        f4 w3 = b4f(*(const us4*)&CW[(i + 3) * 96 + c0]);
        #pragma unroll
        for (int j = 0; j < 8; ++j) {
            f4 hv = *(const f4*)(h + rows[j] * DIN + i);
            #pragma unroll
            for (int q = 0; q < 4; ++q)
                acc[j][q] = fmaf(hv[3], w3[q],
                            fmaf(hv[2], w2[q],
                            fmaf(hv[1], w1[q],
                            fmaf(hv[0], w0[q], acc[j][q]))));
        }
    }

    if (c0 < 64) {
        #pragma unroll
        for (int j = 0; j < 8; ++j)
            if (base + j < nNodes) {
                us4 v = {f2b(acc[j][0]), f2b(acc[j][1]),
                         f2b(acc[j][2]), f2b(acc[j][3])};
                *(us4*)(hb + (long)(base + j) * 64 + c0) = v;
            }
    } else {
        f4 bv = *(const f4*)(bias + (c0 - 64));
        #pragma unroll
        for (int j = 0; j < 8; ++j)
            if (base + j < nNodes) {
                us4 v = {f2b(acc[j][0] + bv[0]), f2b(acc[j][1] + bv[1]),
                         f2b(acc[j][2] + bv[2]), f2b(acc[j][3] + bv[3])};
                *(us4*)(agg + (long)(base + j) * 32 + (c0 - 64)) = v;
            }
    }
}

// ---------------------------------------------------------------------------
// Contention-free bucketed CSR build (unchanged).
__global__ __launch_bounds__(256)
void k_bhist2(const int* __restrict__ dst, int* __restrict__ hist,
              int nEdges, int nB, int chunk)
{
    __shared__ int hloc[MAXB];
    for (int i = threadIdx.x; i < nB; i += 256) hloc[i] = 0;
    __syncthreads();
    const int ebeg = blockIdx.x * chunk;
    const int eend = min(ebeg + chunk, nEdges);
    for (int e = ebeg + threadIdx.x; e < eend; e += 256)
        atomicAdd(&hloc[dst[e] >> 8], 1);
    __syncthreads();
    for (int i = threadIdx.x; i < nB; i += 256)
        hist[blockIdx.x * MAXB + i] = hloc[i];
}

__global__ __launch_bounds__(256)
void k_colscan(const int* __restrict__ hist, int* __restrict__ base,
               int* __restrict__ colsum, int nB)
{
    __shared__ int s[256];
    const int b = blockIdx.x;
    const int t = threadIdx.x;
    int v = hist[t * MAXB + b];
    s[t] = v; __syncthreads();
    for (int off = 1; off < 256; off <<= 1) {
        int tmp = (t >= off) ? s[t - off] : 0;
        __syncthreads();
        s[t] += tmp;
        __syncthreads();
    }
    base[t * MAXB + b] = s[t] - v;
    if (t == 255) colsum[b] = s[255];
}

__global__ __launch_bounds__(1024)
void k_bscan2(const int* __restrict__ colsum, int* __restrict__ bb,
              int* __restrict__ rowptr, int nB, int nNodes, int nEdges)
{
    __shared__ int s[1024];
    int t = threadIdx.x;
    int v = (t < nB) ? colsum[t] : 0;
    s[t] = v; __syncthreads();
    for (int off = 1; off < 1024; off <<= 1) {
        int tmp = (t >= off) ? s[t - off] : 0;
        __syncthreads();
        s[t] += tmp;
        __syncthreads();
    }
    if (t < nB) bb[t] = s[t] - v;
    if (t == 0) { bb[nB] = nEdges; rowptr[nNodes] = nEdges; }
}

__global__ __launch_bounds__(256)
void k_bscatter2(const int* __restrict__ src, const int* __restrict__ dst,
                 const int* __restrict__ et, const int* __restrict__ base,
                 const int* __restrict__ bb, unsigned* __restrict__ bpk,
                 int nEdges, int nB, int chunk)
{
    __shared__ int sbase[MAXB];
    __shared__ int cur[MAXB];
    for (int i = threadIdx.x; i < nB; i += 256) {
        sbase[i] = bb[i] + base[blockIdx.x * MAXB + i];
        cur[i] = 0;
    }
    __syncthreads();
    const int ebeg = blockIdx.x * chunk;
    const int eend = min(ebeg + chunk, nEdges);
    for (int e = ebeg + threadIdx.x; e < eend; e += 256) {
        int d = dst[e];
        int b = d >> 8;
        int r = atomicAdd(&cur[b], 1);
        bpk[sbase[b] + r] = ((unsigned)(d & 255) << 21)
                          | ((unsigned)src[e] << 3) | (unsigned)et[e];
    }
}

__global__ __launch_bounds__(256)
void k_bucket(const unsigned* __restrict__ bpk, const int* __restrict__ bbase,
              int* __restrict__ rowptr, unsigned* __restrict__ packed, int nNodes)
{
    __shared__ int s[256];
    __shared__ int cur[256];
    const int b = blockIdx.x;
    const int t = threadIdx.x;
    const int ebeg = bbase[b], eend = bbase[b + 1];

    cur[t] = 0;
    __syncthreads();
    for (int j = ebeg + t; j < eend; j += 256)
        atomicAdd(&cur[bpk[j] >> 21], 1);
    __syncthreads();
    int v = cur[t];
    s[t] = v; __syncthreads();
    for (int off = 1; off < 256; off <<= 1) {
        int tmp = (t >= off) ? s[t - off] : 0;
        __syncthreads();
        s[t] += tmp;
        __syncthreads();
    }
    int ex = s[t] - v;
    int node = b * 256 + t;
    if (node < nNodes) rowptr[node] = ebeg + ex;
    cur[t] = ex;
    __syncthreads();
    for (int j = ebeg + t; j < eend; j += 256) {
        unsigned p = bpk[j];
        int pos = ebeg + atomicAdd(&cur[p >> 21], 1);
        packed[pos] = p & 0x1FFFFFu;
    }
}

// ---------------------------------------------------------------------------
// Referenced-node set: flags from the 4 index arrays, then compaction.
__global__ __launch_bounds__(256)
void k_zerof(int* __restrict__ flags4, int n4, int* __restrict__ cnt)
{
    int i = blockIdx.x * 256 + threadIdx.x;
    if (i < n4) flags4[i] = 0;
    if (i == 0) *cnt = 0;
}

__global__ __launch_bounds__(256)
void k_flags(const int* __restrict__ ui, const int* __restrict__ ii,
             const int* __restrict__ tes, const int* __restrict__ ted,
             int U, int T, unsigned char* __restrict__ flags)
{
    int g = blockIdx.x * 256 + threadIdx.x;
    int idx;
    if (g < U)               idx = ui[g];
    else if (g < 2 * U)      idx = ii[g - U];
    else if (g < 2 * U + T)  idx = tes[g - 2 * U];
    else if (g < 2 * U + 2 * T) idx = ted[g - 2 * U - T];
    else return;
    flags[idx] = 1;
}

__global__ __launch_bounds__(256)
void k_compact(const unsigned char* __restrict__ flags, int* __restrict__ list,
               int* __restrict__ cnt, int n)
{
    __shared__ int s[256];
    __shared__ int bofs;
    int t = threadIdx.x;
    int i = blockIdx.x * 256 + t;
    int f = (i < n) ? (int)flags[i] : 0;
    s[t] = f; __syncthreads();
    for (int off = 1; off < 256; off <<= 1) {
        int v = (t >= off) ? s[t - off] : 0;
        __syncthreads();
        s[t] += v;
        __syncthreads();
    }
    if (t == 255) bofs = atomicAdd(cnt, s[255]);
    __syncthreads();
    if (f) list[bofs + s[t] - 1] = i;
}

// ---------------------------------------------------------------------------
// Layer-0 pull (bf16 hb gather).
__global__ __launch_bounds__(256)
void k_pull0(const int* __restrict__ rowptr, const unsigned* __restrict__ packed,
             const float* __restrict__ comb, const u16* __restrict__ hb,
             u16* __restrict__ h0, int nNodes)
{
    __shared__ float sc[16];
    if (threadIdx.x < 16) sc[threadIdx.x] = comb[threadIdx.x];
    __syncthreads();
    int n = blockIdx.x * 4 + (threadIdx.x >> 6);
    if (n >= nNodes) return;
    int lane = threadIdx.x & 63, o = lane & 31, half = lane >> 5;
    int beg = rowptr[n], end = rowptr[n + 1];
    float acc = 0.f;
    int j = beg + half;
    for (; j + 2 < end; j += 4) {
        unsigned pa = packed[j], pb = packed[j + 2];
        const u16* ha = hb + (long)(pa >> 3) * 64;
        const u16* hc = hb + (long)(pb >> 3) * 64;
        float a0 = b2f(ha[o]), a1 = b2f(ha[32 + o]);
        float b0 = b2f(hc[o]), b1 = b2f(hc[32 + o]);
        int ra = (pa & 7) * 2, rb = (pb & 7) * 2;
        acc = fmaf(sc[ra], a0, fmaf(sc[ra + 1], a1, acc));
        acc = fmaf(sc[rb], b0, fmaf(sc[rb + 1], b1, acc));
    }
    if (j < end) {
        unsigned pa = packed[j];
        const u16* ha = hb + (long)(pa >> 3) * 64;
        int ra = (pa & 7) * 2;
        acc = fmaf(sc[ra], b2f(ha[o]), fmaf(sc[ra + 1], b2f(ha[32 + o]), acc));
    }
    acc += __shfl_xor(acc, 32);
    if (half == 0) {
        long idx = (long)n * 32 + o;
        h0[idx] = f2b(tanhf(b2f(h0[idx]) + acc));
    }
}

// ---------------------------------------------------------------------------
// Layers 1/2 pull in INPUT space; u stored bf16.
__global__ __launch_bounds__(256)
void k_pull_u(const int* __restrict__ rowptr, const unsigned* __restrict__ packed,
              const float* __restrict__ comb, const u16* __restrict__ hsrc,
              u16* __restrict__ u, int nNodes)
{
    __shared__ float sc[16];
    if (threadIdx.x < 16) sc[threadIdx.x] = comb[threadIdx.x];
    __syncthreads();
    int n = blockIdx.x * 4 + (threadIdx.x >> 6);
    if (n >= nNodes) return;
    int lane = threadIdx.x & 63, i = lane & 31, half = lane >> 5;
    int beg = rowptr[n], end = rowptr[n + 1];
    float u0 = 0.f, u1 = 0.f;
    int j = beg + half;
    for (; j + 2 < end; j += 4) {
        unsigned pa = packed[j], pb = packed[j + 2];
        float ha = b2f(hsrc[(long)(pa >> 3) * 32 + i]);
        float hc = b2f(hsrc[(long)(pb >> 3) * 32 + i]);
        int ra = (pa & 7) * 2, rb = (pb & 7) * 2;
        u0 = fmaf(sc[ra], ha, u0);  u1 = fmaf(sc[ra + 1], ha, u1);
        u0 = fmaf(sc[rb], hc, u0);  u1 = fmaf(sc[rb + 1], hc, u1);
    }
    if (j < end) {
        unsigned pa = packed[j];
        float ha = b2f(hsrc[(long)(pa >> 3) * 32 + i]);
        int ra = (pa & 7) * 2;
        u0 = fmaf(sc[ra], ha, u0);  u1 = fmaf(sc[ra + 1], ha, u1);
    }
    u0 += __shfl_xor(u0, 32);
    u1 += __shfl_xor(u1, 32);
    if (half == 0) {
        u[(long)n * 64 + i]      = f2b(u0);
        u[(long)n * 64 + 32 + i] = f2b(u1);
    }
}

// ---------------------------------------------------------------------------
// Post GEMM for layers 1/2: hdst = tanh([u0|u1|hsrc] @ [V0;V1;loop] + bias).
__global__ __launch_bounds__(256, 2)
void k_post(const u16* __restrict__ u, const u16* __restrict__ hsrc,
            const float* __restrict__ V, const float* __restrict__ loopw,
            const float* __restrict__ bias, u16* __restrict__ hdst, int nNodes)
{
    __shared__ float CW[96 * 32];
    for (int idx = threadIdx.x; idx < 96 * 32; idx += 256) {
        int i = idx / 32, o = idx % 32;
        CW[idx] = (i < 64) ? V[i * 32 + o]
                           : loopw[(i - 64) * 32 + o];
    }
    __syncthreads();

    const int cg = threadIdx.x & 7;
    const int ng = threadIdx.x >> 3;
    const int c0 = cg * 4;
    const int base = blockIdx.x * 128 + ng * 4;
    if (base >= nNodes) return;

    long rows[4];
    #pragma unroll
    for (int j = 0; j < 4; ++j)
        rows[j] = (long)min(base + j, nNodes - 1);

    float acc[4][4] = {};
    #pragma unroll 2
    for (int i = 0; i < 96; i += 4) {
        f4 w0 = *(const f4*)&CW[(i + 0) * 32 + c0];
        f4 w1 = *(const f4*)&CW[(i + 1) * 32 + c0];
        f4 w2 = *(const f4*)&CW[(i + 2) * 32 + c0];
        f4 w3 = *(const f4*)&CW[(i + 3) * 32 + c0];
        #pragma unroll
        for (int j = 0; j < 4; ++j) {
            f4 hv;
            if (i < 64) hv = b4f(*(const us4*)(u + rows[j] * 64 + i));
            else        hv = b4f(*(const us4*)(hsrc + rows[j] * 32 + (i - 64)));
            #pragma unroll
            for (int q = 0; q < 4; ++q)
                acc[j][q] = fmaf(hv[3], w3[q],
                            fmaf(hv[2], w2[q],
                            fmaf(hv[1], w1[q],
                            fmaf(hv[0], w0[q], acc[j][q]))));
        }
    }

    f4 bv = *(const f4*)(bias + c0);
    #pragma unroll
    for (int j = 0; j < 4; ++j)
        if (base + j < nNodes) {
            us4 v = {f2b(tanhf(acc[j][0] + bv[0])), f2b(tanhf(acc[j][1] + bv[1])),
                     f2b(tanhf(acc[j][2] + bv[2])), f2b(tanhf(acc[j][3] + bv[3]))};
            *(us4*)(hdst + (long)(base + j) * 32 + c0) = v;
        }
}

// ---------------------------------------------------------------------------
// Fused MLP heads + reparameterization over the COMPACTED node list only.
__global__ __launch_bounds__(256, 2)
void k_mlp(const u16* __restrict__ h0, const u16* __restrict__ h1,
           const u16* __restrict__ h2,
           const float* __restrict__ Wm1, const float* __restrict__ bm1,
           const float* __restrict__ Wm2, const float* __restrict__ bm2,
           const float* __restrict__ Ws1, const float* __restrict__ bs1,
           const float* __restrict__ Ws2, const float* __restrict__ bs2,
           const float* __restrict__ noise, float* __restrict__ z,
           const int* __restrict__ list, const int* __restrict__ cnt)
{
    const int count = *cnt;
    const int base = blockIdx.x * 64;
    if (base >= count) return;

    __shared__ float sW1[2][96 * 32];
    __shared__ float sW2[2][32 * 128];
    __shared__ float sb1[2][32];
    __shared__ float sb2[2][128];
    __shared__ float shid[2][64][32];

    for (int i = threadIdx.x; i < 96 * 32; i += 256) { sW1[0][i] = Wm1[i]; sW1[1][i] = Ws1[i]; }
    for (int i = threadIdx.x; i < 32 * 128; i += 256) { sW2[0][i] = Wm2[i]; sW2[1][i] = Ws2[i]; }
    if (threadIdx.x < 32)  { sb1[0][threadIdx.x] = bm1[threadIdx.x]; sb1[1][threadIdx.x] = bs1[threadIdx.x]; }
    if (threadIdx.x < 128) { sb2[0][threadIdx.x] = bm2[threadIdx.x]; sb2[1][threadIdx.x] = bs2[threadIdx.x]; }
    __syncthreads();

    // ---- phase A: hidden = relu(cs @ W1 + b1) ----
    {
        const int head = threadIdx.x >> 7;
        const int rem  = threadIdx.x & 127;
        const int ng   = rem >> 3;
        const int c0   = (rem & 7) * 4;
        const float* sW = sW1[head];
        long rows[4];
        #pragma unroll
        for (int j = 0; j < 4; ++j)
            rows[j] = (long)list[min(base + ng * 4 + j, count - 1)];

        float acc[4][4] = {};
        const u16* hs[3] = {h0, h1, h2};
        #pragma unroll
        for (int part = 0; part < 3; ++part) {
            const u16* hp = hs[part];
            #pragma unroll
            for (int kk = 0; kk < 32; kk += 4) {
                const int k = part * 32 + kk;
                f4 w0 = *(const f4*)&sW[(k + 0) * 32 + c0];
                f4 w1 = *(const f4*)&sW[(k + 1) * 32 + c0];
                f4 w2 = *(const f4*)&sW[(k + 2) * 32 + c0];
                f4 w3 = *(const f4*)&sW[(k + 3) * 32 + c0];
                #pragma unroll
                for (int j = 0; j < 4; ++j) {
                    f4 hv = b4f(*(const us4*)(hp + rows[j] * 32 + kk));
                    #pragma unroll
                    for (int q = 0; q < 4; ++q)
                        acc[j][q] = fmaf(hv[3], w3[q],
                                    fmaf(hv[2], w2[q],
                                    fmaf(hv[1], w1[q],
                                    fmaf(hv[0], w0[q], acc[j][q]))));
                }
            }
        }
        f4 bv = *(const f4*)&sb1[head][c0];
        #pragma unroll
        for (int j = 0; j < 4; ++j) {
            f4 v = {fmaxf(acc[j][0] + bv[0], 0.f), fmaxf(acc[j][1] + bv[1], 0.f),
                    fmaxf(acc[j][2] + bv[2], 0.f), fmaxf(acc[j][3] + bv[3], 0.f)};
            *(f4*)&shid[head][ng * 4 + j][c0] = v;
        }
    }
    __syncthreads();

    // ---- phase B: out = hid @ W2 + b2; z = mean + noise * exp(log_std) ----
    const int ng = threadIdx.x >> 5;
    const int c0 = (threadIdx.x & 31) * 4;
    #pragma unroll
    for (int pass = 0; pass < 2; ++pass) {
        const int nb = pass * 32 + ng * 4;
        float am[4][4] = {}, as_[4][4] = {};
        #pragma unroll 4
        for (int k = 0; k < 32; k += 4) {
            f4 wm0 = *(const f4*)&sW2[0][(k + 0) * 128 + c0];
            f4 wm1 = *(const f4*)&sW2[0][(k + 1) * 128 + c0];
            f4 wm2 = *(const f4*)&sW2[0][(k + 2) * 128 + c0];
            f4 wm3 = *(const f4*)&sW2[0][(k + 3) * 128 + c0];
            f4 ws0 = *(const f4*)&sW2[1][(k + 0) * 128 + c0];
            f4 ws1 = *(const f4*)&sW2[1][(k + 1) * 128 + c0];
            f4 ws2 = *(const f4*)&sW2[1][(k + 2) * 128 + c0];
            f4 ws3 = *(const f4*)&sW2[1][(k + 3) * 128 + c0];
            #pragma unroll
            for (int j = 0; j < 4; ++j) {
                f4 hm = *(const f4*)&shid[0][nb + j][k];
                f4 hv = *(const f4*)&shid[1][nb + j][k];
                #pragma unroll
                for (int q = 0; q < 4; ++q) {
                    am[j][q]  = fmaf(hm[3], wm3[q],
                                fmaf(hm[2], wm2[q],
                                fmaf(hm[1], wm1[q],
                                fmaf(hm[0], wm0[q], am[j][q]))));
                    as_[j][q] = fmaf(hv[3], ws3[q],
                                fmaf(hv[2], ws2[q],
                                fmaf(hv[1], ws1[q],
                                fmaf(hv[0], ws0[q], as_[j][q]))));
                }
            }
        }
        f4 b2m = *(const f4*)&sb2[0][c0];
        f4 b2s = *(const f4*)&sb2[1][c0];
        #pragma unroll
        for (int j = 0; j < 4; ++j) {
            const int idx = base + nb + j;
            if (idx < count) {
                const long n = (long)list[idx];
                f4 nz = *(const f4*)(noise + n * 128 + c0);
                f4 v;
                #pragma unroll
                for (int q = 0; q < 4; ++q)
                    v[q] = fmaf(nz[q], expf(as_[j][q] + b2s[q]), am[j][q] + b2m[q]);
                *(f4*)(z + n * 128 + c0) = v;
            }
        }
    }
}

// ---------------------------------------------------------------------------
__global__ __launch_bounds__(256)
void k_pairs(const float* __restrict__ z, const int* __restrict__ ui,
             const int* __restrict__ ii, float* __restrict__ out, int U, int T)
{
    int w = (blockIdx.x * 256 + threadIdx.x) >> 6;
    int lane = threadIdx.x & 63;
    if (w >= U) return;
    int a = ui[w], b = ii[w];
    float a0 = z[(long)a * 128 + lane], a1 = z[(long)a * 128 + 64 + lane];
    float b0 = z[(long)b * 128 + lane], b1 = z[(long)b * 128 + 64 + lane];
    float* res = out + U + T;
    res[(long)w * 128 + lane] = a0;
    res[(long)w * 128 + 64 + lane] = a1;
    res[(long)(U + w) * 128 + lane] = b0;
    res[(long)(U + w) * 128 + 64 + lane] = b1;
    float d = fmaf(a0, b0, a1 * b1);
    #pragma unroll
    for (int off = 32; off; off >>= 1) d += __shfl_xor(d, off);
    if (lane == 0) out[w] = d;
}

__global__ __launch_bounds__(256)
void k_preds(const float* __restrict__ z, const int* __restrict__ ts,
             const int* __restrict__ td, float* __restrict__ out, int U, int T)
{
    int w = (blockIdx.x * 256 + threadIdx.x) >> 6;
    int lane = threadIdx.x & 63;
    if (w >= T) return;
    int a = ts[w], b = td[w];
    float a0 = z[(long)a * 128 + lane], a1 = z[(long)a * 128 + 64 + lane];
    float b0 = z[(long)b * 128 + lane], b1 = z[(long)b * 128 + 64 + lane];
    float d = fmaf(a0, b0, a1 * b1);
    #pragma unroll
    for (int off = 32; off; off >>= 1) d += __shfl_xor(d, off);
    if (lane == 0) out[U + w] = d;
}

// ---------------------------------------------------------------------------
extern "C" void kernel_launch(void* const* d_in, const int* in_sizes, int n_in,
                              void* d_out, int out_size, void* d_ws, size_t ws_size,
                              hipStream_t stream)
{
    const float* x     = (const float*)d_in[0];
    const int*   src   = (const int*)d_in[1];
    const int*   dst   = (const int*)d_in[2];
    const int*   et    = (const int*)d_in[3];
    const float* noise = (const float*)d_in[4];
    const int*   ui    = (const int*)d_in[5];
    const int*   ii    = (const int*)d_in[6];
    const int*   tes   = (const int*)d_in[7];
    const int*   ted   = (const int*)d_in[8];
    const float* V0    = (const float*)d_in[9];
    const float* comb0 = (const float*)d_in[10];
    const float* loop0 = (const float*)d_in[11];
    const float* b0    = (const float*)d_in[12];
    const float* V1    = (const float*)d_in[13];
    const float* comb1 = (const float*)d_in[14];
    const float* loop1 = (const float*)d_in[15];
    const float* b1    = (const float*)d_in[16];
    const float* V2    = (const float*)d_in[17];
    const float* comb2 = (const float*)d_in[18];
    const float* loop2 = (const float*)d_in[19];
    const float* b2    = (const float*)d_in[20];
    const float* Wm1   = (const float*)d_in[21];
    const float* bm1   = (const float*)d_in[22];
    const float* Wm2   = (const float*)d_in[23];
    const float* bm2   = (const float*)d_in[24];
    const float* Ws1   = (const float*)d_in[25];
    const float* bs1   = (const float*)d_in[26];
    const float* Ws2   = (const float*)d_in[27];
    const float* bs2   = (const float*)d_in[28];

    const int N = in_sizes[0] / 128;   // 200000
    const int E = in_sizes[1];         // 3200000
    const int U = in_sizes[5];
    const int T = in_sizes[7];
    const int NB = (N + 255) / 256;    // 782 buckets
    const int chunk = (E + NBLK - 1) / NBLK;

    float* out = (float*)d_out;

    // Workspace layout (bytes):
    //  hb  bf16 [N][64] | h0/h1/h2 bf16 [N][32] | u bf16 [N][64]
    //  z f32 [N][128]  (CSR int scratch aliases z; dead by k_mlp)
    //  flags char[N] | list int[N] | cnt int   (after z -> never aliases)
    char* W = (char*)d_ws;
    u16*   hb = (u16*)W;
    u16*   h0 = (u16*)(W + (size_t)N * 64 * 2);
    u16*   h1 = h0 + (size_t)N * 32;
    u16*   h2 = h1 + (size_t)N * 32;
    u16*   u  = (u16*)(W + (size_t)N * 64 * 2 + (size_t)N * 32 * 2 * 3);
    float* z  = (float*)(u + (size_t)N * 64);
    unsigned char* flags = (unsigned char*)(z + (size_t)N * 128);
    int*   list = (int*)(flags + (size_t)N);
    int*   cnt  = list + N;

    int*      rowptr = (int*)z;
    unsigned* packed = (unsigned*)(rowptr + N + 1);
    unsigned* bpk    = packed + E;
    int*      hist   = (int*)(bpk + E);
    int*      basep  = hist + NBLK * MAXB;
    int*      colsum = basep + NBLK * MAXB;
    int*      bb     = colsum + NB;

    const int hbBlocks   = (N + 63) / 64;
    const int pullBlocks = (N + 3) / 4;
    const int postBlocks = (N + 127) / 128;
    const int mlpBlocks  = (N + 63) / 64;   // upper bound; blocks self-limit by cnt

    // ---- referenced-node flags + compaction ----
    k_zerof<<<(N / 4 + 255) / 256, 256, 0, stream>>>((int*)flags, N / 4, cnt);
    k_flags<<<(2 * U + 2 * T + 255) / 256, 256, 0, stream>>>(ui, ii, tes, ted, U, T, flags);
    k_compact<<<NB, 256, 0, stream>>>(flags, list, cnt, N);

    // ---- contention-free bucketed CSR build (by dst) ----
    k_bhist2<<<NBLK, 256, 0, stream>>>(dst, hist, E, NB, chunk);
    k_colscan<<<NB, 256, 0, stream>>>(hist, basep, colsum, NB);
    k_bscan2<<<1, 1024, 0, stream>>>(colsum, bb, rowptr, NB, N, E);
    k_bscatter2<<<NBLK, 256, 0, stream>>>(src, dst, et, basep, bb, bpk, E, NB, chunk);
    k_bucket<<<NB, 256, 0, stream>>>(bpk, bb, rowptr, packed, N);

    // ---- layer 0 ----
    k_hb<128><<<hbBlocks, 192, 0, stream>>>(x, V0, loop0, b0, hb, h0, N);
    k_pull0<<<pullBlocks, 256, 0, stream>>>(rowptr, packed, comb0, hb, h0, N);

    // ---- layer 1 ----
    k_pull_u<<<pullBlocks, 256, 0, stream>>>(rowptr, packed, comb1, h0, u, N);
    k_post<<<postBlocks, 256, 0, stream>>>(u, h0, V1, loop1, b1, h1, N);

    // ---- layer 2 ----
    k_pull_u<<<pullBlocks, 256, 0, stream>>>(rowptr, packed, comb2, h1, u, N);
    k_post<<<postBlocks, 256, 0, stream>>>(u, h1, V2, loop2, b2, h2, N);

    // ---- heads + reparameterization (compacted) ----
    k_mlp<<<mlpBlocks, 256, 0, stream>>>(h0, h1, h2, Wm1, bm1, Wm2, bm2,
                                         Ws1, bs1, Ws2, bs2, noise, z, list, cnt);
    // ---- outputs ----
    k_pairs<<<(U * 64 + 255) / 256, 256, 0, stream>>>(z, ui, ii, out, U, T);
    k_preds<<<(T * 64 + 255) / 256, 256, 0, stream>>>(z, tes, ted, out, U, T);
}